// Round 12
// baseline (321.107 us; speedup 1.0000x reference)
//
#include <hip/hip_runtime.h>
#include <hip/hip_bf16.h>
#include <math.h>

#define D_MODEL 512
#define SEQ     2048
#define BATCH   4
#define NHEADS  8
#define HDIM    64
#define FFN     2048
#define TOKENS  (BATCH*SEQ)

typedef __attribute__((ext_vector_type(8))) short bf16x8;
typedef __attribute__((ext_vector_type(4))) float f32x4;
typedef __attribute__((ext_vector_type(4))) unsigned u32x4;

__device__ inline ushort f2bf(float f) {
    unsigned u = __builtin_bit_cast(unsigned, f);
    unsigned r = (u + 0x7fffu + ((u >> 16) & 1u)) >> 16;   // RNE
    return (ushort)r;
}

#define GLOAD_LDS16(g, l) __builtin_amdgcn_global_load_lds( \
    (const __attribute__((address_space(1))) void*)(g), \
    (__attribute__((address_space(3))) void*)(l), 16, 0, 0)

// ---------------- fused fp32 -> bf16 cast of x,Wqkv,Wo,W1,W2 (outputs contiguous)
__global__ void cast_all_bf16(const float* __restrict__ x, const float* __restrict__ Wqkv,
                              const float* __restrict__ Wo, const float* __restrict__ W1,
                              const float* __restrict__ W2, ushort* __restrict__ outbase) {
    const int i = blockIdx.x * blockDim.x + threadIdx.x;   // float4 index
    if (i >= 1835008) return;
    float4 v;
    if      (i < 1048576) v = ((const float4*)x)[i];
    else if (i < 1245184) v = ((const float4*)Wqkv)[i - 1048576];
    else if (i < 1310720) v = ((const float4*)Wo)[i - 1245184];
    else if (i < 1572864) v = ((const float4*)W1)[i - 1310720];
    else                  v = ((const float4*)W2)[i - 1572864];
    ushort4 o;
    o.x = f2bf(v.x); o.y = f2bf(v.y); o.z = f2bf(v.z); o.w = f2bf(v.w);
    ((ushort4*)outbase)[i] = o;
}

// ---------------- bf16 MFMA GEMM: C[M,N] = A[M,Kstride] @ W[N,Kstride]^T + bias
// MODE 1: bf16 out (+optional ReLU). MODE 2: qkv-split out. MODE 3: fp32 out
// with bias (full-K).
// Tile BM x BN; BN=128 -> 4 waves (2x2, 256 thr), BN=256 -> 8 waves (2x4,
// 512 thr). Wave output = (BM/2) x 64.
//   QKV: 128x128, 768 blk @3/CU (48KB) = 1 exact round
//   Wo/FF2: 64x128, 512 blk @4/CU (36KB) = 1 round
//   FF1: 128x256, 512 blk @2/CU (72KB, 16 waves/CU) = 1 exact round, 2x
//        B-reuse (round-9/10 A/B: ~5us gain vs 128-wide variants)
//
// Depth-3 K-pipeline with COUNTED vmcnt (T4): 3 LDS buffer pairs; per tile
// exactly one {s_waitcnt vmcnt(L); s_barrier}, L = loads/thread of one stage.
// Stage issued for t+2 right after the barrier stays in flight across TWO
// barriers. WAR safety: stage(t+2) overwrites the buffer computed at t-1;
// every wave passed barrier t only after finishing compute(t-1).
//
// XCD-grouped swizzle (T1): flat id f -> XCD f%8 owns gridDim.y/8
// consecutive m-panels x all n-blocks, n fastest.
//
// Bank-conflict swizzle (rule #21, verified conflicts->0): LDS slot
// (row, q16) holds global quarter q16 ^ ((row>>1)&3); LDS dest of
// global_load_lds stays LINEAR, global SOURCE column pre-swizzled, fragment
// reads XOR the same term.
// NO setprio in GEMM (catalog m190: null-to-negative without phase-split).
template<int MODE, int RELU, int BM, int BN>
__global__ __launch_bounds__(BN == 256 ? 512 : 256)
void gemm_bt_mfma(const ushort* __restrict__ A,
                  const ushort* __restrict__ W,
                  const float* __restrict__ bias,
                  void* __restrict__ CoutA,
                  ushort* __restrict__ Qc,
                  ushort* __restrict__ Kc,
                  ushort* __restrict__ Vt,
                  int M, int N, int Kstride, int Klen) {
    constexpr int NW    = (BN == 256) ? 8 : 4;   // waves per block
    constexpr int WC    = NW / 2;                // wave columns
    constexpr int MI    = BM / 32;               // m-fragments per wave
    constexpr int AROWS = BM / NW;               // A rows staged per wave (16/32)
    constexpr bool A2   = (AROWS == 32);         // second A load?
    __shared__ ushort Asb[3][BM * 32];
    __shared__ ushort Bsb[3][BN * 32];

    const int tid  = threadIdx.x;
    const int lane = tid & 63;
    const int wv   = tid >> 6;

    const int Gx = gridDim.x;
    const int f  = blockIdx.x + Gx * blockIdx.y;
    const int xc = f & 7;                 // XCD under %8 round-robin
    const int j  = f >> 3;
    const int ni = j % Gx;                // n fastest within the XCD
    const int mi = xc * (gridDim.y >> 3) + j / Gx;
    const int m0 = mi * BM;
    const int n0 = ni * BN;

    const int wm = (wv / WC) * (BM / 2);
    const int wn = (wv % WC) * 64;

    // staging: thread covers LDS slot row rA/rB, 16B-quarter (lane&3).
    // source column quarter = (lane&3) ^ s(row), s(row)=(row>>1)&3=(lane>>3)&3
    const int rA = wv * AROWS + (lane >> 2);
    const int rB = wv * 32 + (lane >> 2);
    const int cS = (((lane & 3) ^ ((lane >> 3) & 3)) * 8);
    const ushort* gA0 = A + (size_t)(m0 + rA) * Kstride + cS;
    const ushort* gA1 = gA0 + (size_t)16 * Kstride;     // used only if A2
    const ushort* gB0 = W + (size_t)(n0 + rB) * Kstride + cS;
    const ushort* gB1 = gB0 + (size_t)16 * Kstride;

    f32x4 acc[MI][4] = {};

    const int fr  = lane & 15;
    // fragment read: global quarter (lane>>4) of row r sits in LDS quarter
    // (lane>>4) ^ s(r); s(r) = (fr>>1)&3 independent of wm/i.
    const int fks = (((lane >> 4) ^ ((fr >> 1) & 3)) * 8);
    const int loA = wv * (AROWS * 32);    // this wave's A staging strip (ushorts)
    const int loB = wv * 1024;

#define STAGE(ab, bb) do { \
        GLOAD_LDS16(gA0, (ab) + loA); \
        if constexpr (A2) GLOAD_LDS16(gA1, (ab) + loA + 512); \
        GLOAD_LDS16(gB0, (bb) + loB); \
        GLOAD_LDS16(gB1, (bb) + loB + 512); \
        gA0 += 32; if constexpr (A2) gA1 += 32; \
        gB0 += 32; gB1 += 32; } while (0)

#define COMPUTE(ab, bb) do { \
        bf16x8 af_[MI], bf_[4]; \
        _Pragma("unroll") \
        for (int i_ = 0; i_ < MI; ++i_) \
            af_[i_] = *(const bf16x8*)((ab) + (wm + i_ * 16 + fr) * 32 + fks); \
        _Pragma("unroll") \
        for (int j_ = 0; j_ < 4; ++j_) \
            bf_[j_] = *(const bf16x8*)((bb) + (wn + j_ * 16 + fr) * 32 + fks); \
        _Pragma("unroll") \
        for (int i_ = 0; i_ < MI; ++i_) \
            _Pragma("unroll") \
            for (int j_ = 0; j_ < 4; ++j_) \
                acc[i_][j_] = __builtin_amdgcn_mfma_f32_16x16x32_bf16(af_[i_], bf_[j_], acc[i_][j_], 0, 0, 0); \
        } while (0)

#define PWAIT do { \
        if constexpr (A2) asm volatile("s_waitcnt vmcnt(4)" ::: "memory"); \
        else              asm volatile("s_waitcnt vmcnt(3)" ::: "memory"); \
        __builtin_amdgcn_s_barrier(); \
        __builtin_amdgcn_sched_barrier(0); } while (0)

    ushort *Ac = Asb[0], *An = Asb[1], *As = Asb[2];
    ushort *Bc = Bsb[0], *Bn = Bsb[1], *Bs = Bsb[2];

    STAGE(Ac, Bc);                        // tile 0
    STAGE(An, Bn);                        // tile 1
    const int ntiles = Klen >> 5;         // >= 8 for all our shapes
    for (int t = 0; t < ntiles - 1; ++t) {
        PWAIT;
        if (t + 2 < ntiles) STAGE(As, Bs);
        COMPUTE(Ac, Bc);
        ushort* tA = Ac; Ac = An; An = As; As = tA;
        ushort* tB = Bc; Bc = Bn; Bn = Bs; Bs = tB;
    }
    asm volatile("s_waitcnt vmcnt(0)" ::: "memory");
    __builtin_amdgcn_s_barrier();
    __builtin_amdgcn_sched_barrier(0);
    COMPUTE(Ac, Bc);

#undef STAGE
#undef COMPUTE
#undef PWAIT

    const int col  = lane & 15;
    const int rowq = (lane >> 4) * 4;
    #pragma unroll
    for (int i = 0; i < MI; ++i) {
        const int gm = m0 + wm + i * 16 + rowq;
        #pragma unroll
        for (int j2 = 0; j2 < 4; ++j2) {
            const int gn = n0 + wn + j2 * 16 + col;
            if (MODE == 2) {
                const float bv = bias[gn];
                const int seg = gn >> 9;
                const int h   = (gn >> 6) & 7;
                const int dd  = gn & 63;
                const int bb  = gm >> 11;
                const int ss  = gm & 2047;
                const int bh  = bb * 8 + h;
                if (seg == 2) {
                    ushort4 pk;
                    pk.x = f2bf(acc[i][j2][0] + bv);
                    pk.y = f2bf(acc[i][j2][1] + bv);
                    pk.z = f2bf(acc[i][j2][2] + bv);
                    pk.w = f2bf(acc[i][j2][3] + bv);
                    *(ushort4*)(Vt + ((size_t)bh * 64 + dd) * 2048 + ss) = pk;
                } else {
                    ushort* dst = (seg == 0 ? Qc : Kc) + ((size_t)bh * 2048 + ss) * 64 + dd;
                    #pragma unroll
                    for (int r = 0; r < 4; ++r)
                        dst[(size_t)r * 64] = f2bf(acc[i][j2][r] + bv);
                }
            } else if (MODE == 3) {
                float* dst = (float*)CoutA;
                const float bv = bias[gn];
                #pragma unroll
                for (int r = 0; r < 4; ++r)
                    dst[(size_t)(gm + r) * N + gn] = acc[i][j2][r] + bv;
            } else {
                const float bv = bias[gn];
                #pragma unroll
                for (int r = 0; r < 4; ++r) {
                    float v = acc[i][j2][r] + bv;
                    if (RELU) v = fmaxf(v, 0.f);
                    ((ushort*)CoutA)[(size_t)(gm + r) * N + gn] = f2bf(v);
                }
            }
        }
    }
}

// ---------------- fused A/B q-tile step over one 64-row KV tile, fragments
// read DIRECTLY FROM GLOBAL (L1/L2-resident; see kernel comment). Kt points
// at K rows [j0..j0+63] (row-major, 64 d); Vg at V^T col-window s=j0
// (rows d, stride 2048). Data identical to the old swizzled-LDS path: the
// storage swizzle and read XOR cancel (chunk g <-> offset g*8).
// QK^T SWAPPED (s = mfma(K,Q)); P->A-fragment transpose via cvt_pk +
// permlane32/16 swaps. B computed first so its PV overlaps A's softmax.
__device__ __forceinline__ void attn_step2g(const ushort* __restrict__ Kt,
                                            const ushort* __restrict__ Vg,
                                            bf16x8 qfA0, bf16x8 qfA1,
                                            bf16x8 qfB0, bf16x8 qfB1,
                                            float& lpa, float& lpb,
                                            f32x4 (&oa)[4], f32x4 (&ob)[4],
                                            int qwA, int qwB, int j0,
                                            int q0a, int q0b,
                                            int col, int g) {
    const bool doA = (j0 <= q0a);

    // issue ALL loads first: K needed by QK (first use ~immediately), V needed
    // only after softmax (~200+ cyc later) -- compiler's partial vmcnt waits
    // leave V in flight across the QK+mask+exp chain.
    bf16x8 kf0[4], kf1[4], vf0[4], vf1[4];
    #pragma unroll
    for (int nt = 0; nt < 4; ++nt) {
        const int kr = nt * 16 + col;
        kf0[nt] = *(const bf16x8*)(Kt + kr * 64 + g * 8);
        kf1[nt] = *(const bf16x8*)(Kt + kr * 64 + g * 8 + 32);
    }
    #pragma unroll
    for (int nt = 0; nt < 4; ++nt) {
        const int vr = nt * 16 + col;
        vf0[nt] = *(const bf16x8*)(Vg + (size_t)vr * 2048 + g * 8);
        vf1[nt] = *(const bf16x8*)(Vg + (size_t)vr * 2048 + g * 8 + 32);
    }

    f32x4 sA[4] = {}, sB[4] = {};
    __builtin_amdgcn_s_setprio(1);
    #pragma unroll
    for (int nt = 0; nt < 4; ++nt) {
        sB[nt] = __builtin_amdgcn_mfma_f32_16x16x32_bf16(kf0[nt], qfB0, sB[nt], 0, 0, 0);
        sB[nt] = __builtin_amdgcn_mfma_f32_16x16x32_bf16(kf1[nt], qfB1, sB[nt], 0, 0, 0);
    }
    if (doA) {
        #pragma unroll
        for (int nt = 0; nt < 4; ++nt) {
            sA[nt] = __builtin_amdgcn_mfma_f32_16x16x32_bf16(kf0[nt], qfA0, sA[nt], 0, 0, 0);
            sA[nt] = __builtin_amdgcn_mfma_f32_16x16x32_bf16(kf1[nt], qfA1, sA[nt], 0, 0, 0);
        }
    }
    __builtin_amdgcn_s_setprio(0);

    // ---- B: mask, softmax, PV
    if (j0 == q0b) {
        #pragma unroll
        for (int nt = 0; nt < 4; ++nt)
            #pragma unroll
            for (int r = 0; r < 4; ++r)
                if ((j0 + nt * 16 + 4 * g + r) > (qwB + col)) sB[nt][r] = -INFINITY;
    }
    unsigned WB[8];
    #pragma unroll
    for (int nt = 0; nt < 4; ++nt) {
        float p0 = __expf(sB[nt][0] * 0.125f);
        float p1 = __expf(sB[nt][1] * 0.125f);
        float p2 = __expf(sB[nt][2] * 0.125f);
        float p3 = __expf(sB[nt][3] * 0.125f);
        lpb += (p0 + p1) + (p2 + p3);
        asm("v_cvt_pk_bf16_f32 %0, %1, %2" : "=v"(WB[2 * nt])     : "v"(p0), "v"(p1));
        asm("v_cvt_pk_bf16_f32 %0, %1, %2" : "=v"(WB[2 * nt + 1]) : "v"(p2), "v"(p3));
    }
    asm("v_permlane32_swap_b32 %0, %1" : "+v"(WB[0]), "+v"(WB[2]));
    asm("v_permlane32_swap_b32 %0, %1" : "+v"(WB[1]), "+v"(WB[3]));
    asm("v_permlane32_swap_b32 %0, %1" : "+v"(WB[4]), "+v"(WB[6]));
    asm("v_permlane32_swap_b32 %0, %1" : "+v"(WB[5]), "+v"(WB[7]));
    asm("v_permlane16_swap_b32 %0, %1" : "+v"(WB[0]), "+v"(WB[2]));
    asm("v_permlane16_swap_b32 %0, %1" : "+v"(WB[1]), "+v"(WB[3]));
    asm("v_permlane16_swap_b32 %0, %1" : "+v"(WB[4]), "+v"(WB[6]));
    asm("v_permlane16_swap_b32 %0, %1" : "+v"(WB[5]), "+v"(WB[7]));
    {
        u32x4 wa = {WB[0], WB[1], WB[2], WB[3]};
        u32x4 wb = {WB[4], WB[5], WB[6], WB[7]};
        bf16x8 pf0 = __builtin_bit_cast(bf16x8, wa);
        bf16x8 pf1 = __builtin_bit_cast(bf16x8, wb);
        __builtin_amdgcn_s_setprio(1);
        #pragma unroll
        for (int nt = 0; nt < 4; ++nt) {
            ob[nt] = __builtin_amdgcn_mfma_f32_16x16x32_bf16(pf0, vf0[nt], ob[nt], 0, 0, 0);
            ob[nt] = __builtin_amdgcn_mfma_f32_16x16x32_bf16(pf1, vf1[nt], ob[nt], 0, 0, 0);
        }
        __builtin_amdgcn_s_setprio(0);
    }

    // ---- A: mask, softmax, PV (uniform branch; PV(B) above overlaps this VALU)
    if (doA) {
        if (j0 == q0a) {
            #pragma unroll
            for (int nt = 0; nt < 4; ++nt)
                #pragma unroll
                for (int r = 0; r < 4; ++r)
                    if ((j0 + nt * 16 + 4 * g + r) > (qwA + col)) sA[nt][r] = -INFINITY;
        }
        unsigned WA[8];
        #pragma unroll
        for (int nt = 0; nt < 4; ++nt) {
            float p0 = __expf(sA[nt][0] * 0.125f);
            float p1 = __expf(sA[nt][1] * 0.125f);
            float p2 = __expf(sA[nt][2] * 0.125f);
            float p3 = __expf(sA[nt][3] * 0.125f);
            lpa += (p0 + p1) + (p2 + p3);
            asm("v_cvt_pk_bf16_f32 %0, %1, %2" : "=v"(WA[2 * nt])     : "v"(p0), "v"(p1));
            asm("v_cvt_pk_bf16_f32 %0, %1, %2" : "=v"(WA[2 * nt + 1]) : "v"(p2), "v"(p3));
        }
        asm("v_permlane32_swap_b32 %0, %1" : "+v"(WA[0]), "+v"(WA[2]));
        asm("v_permlane32_swap_b32 %0, %1" : "+v"(WA[1]), "+v"(WA[3]));
        asm("v_permlane32_swap_b32 %0, %1" : "+v"(WA[4]), "+v"(WA[6]));
        asm("v_permlane32_swap_b32 %0, %1" : "+v"(WA[5]), "+v"(WA[7]));
        asm("v_permlane16_swap_b32 %0, %1" : "+v"(WA[0]), "+v"(WA[2]));
        asm("v_permlane16_swap_b32 %0, %1" : "+v"(WA[1]), "+v"(WA[3]));
        asm("v_permlane16_swap_b32 %0, %1" : "+v"(WA[4]), "+v"(WA[6]));
        asm("v_permlane16_swap_b32 %0, %1" : "+v"(WA[5]), "+v"(WA[7]));
        u32x4 wa = {WA[0], WA[1], WA[2], WA[3]};
        u32x4 wb = {WA[4], WA[5], WA[6], WA[7]};
        bf16x8 pf0 = __builtin_bit_cast(bf16x8, wa);
        bf16x8 pf1 = __builtin_bit_cast(bf16x8, wb);
        __builtin_amdgcn_s_setprio(1);
        #pragma unroll
        for (int nt = 0; nt < 4; ++nt) {
            oa[nt] = __builtin_amdgcn_mfma_f32_16x16x32_bf16(pf0, vf0[nt], oa[nt], 0, 0, 0);
            oa[nt] = __builtin_amdgcn_mfma_f32_16x16x32_bf16(pf1, vf1[nt], oa[nt], 0, 0, 0);
        }
        __builtin_amdgcn_s_setprio(0);
    }
}

// ---------------- MFMA flash attention, paired q-tiles, NO LDS / NO BARRIERS.
// Round-12: attn plateaued 38-41us across 6 LDS-staged variants; the common
// structure was a block-wide barrier per 64 KV rows lock-stepping all waves
// onto the serial QK->softmax->PV chain. K/V tiles are 8KB each and L2-hot
// (FETCH ~ 12MB = one pass); the 4 waves of a block read the SAME tile, so
// L1 (32KB = 2 blocks x 16KB) captures the intra-block reuse and per-CU
// unique L2 traffic ~43B/cyc < 58B/cyc ceiling. Reading fragments directly
// from global deletes LDS staging, ds_writes, and ALL barriers -- waves
// de-phase freely and the compiler's partial vmcnt waits pipeline V-loads
// under the QK+softmax chain. 2 blocks/CU (VGPR-bound; round-8 showed
// occupancy beyond this is not the lever).
// XCD swizzle: all 16 pair-blocks of a bh on one XCD (K/V 2MB < 4MB L2).
__global__ __launch_bounds__(256, 2) void attn_mfma_kernel(const ushort* __restrict__ Qc,
                                                           const ushort* __restrict__ Kc,
                                                           const ushort* __restrict__ Vt,
                                                           ushort* __restrict__ ctxb) {
    const int tid  = threadIdx.x;
    const int lane = tid & 63;
    const int wv   = tid >> 6;
    const int idx  = blockIdx.x;                // 0..511
    const int bh   = (idx & 7) * 4 + (idx >> 7);
    const int pair = (idx >> 3) & 15;
    const int q0a  = pair * 64;
    const int q0b  = (31 - pair) * 64;
    const int qwA  = q0a + wv * 16;
    const int qwB  = q0b + wv * 16;

    const int col = lane & 15;
    const int g   = lane >> 4;

    bf16x8 qfA0, qfA1, qfB0, qfB1;
    {
        const ushort* qa = Qc + ((size_t)bh * 2048 + qwA + col) * 64 + g * 8;
        qfA0 = *(const bf16x8*)qa;
        qfA1 = *(const bf16x8*)(qa + 32);
        const ushort* qb = Qc + ((size_t)bh * 2048 + qwB + col) * 64 + g * 8;
        qfB0 = *(const bf16x8*)qb;
        qfB1 = *(const bf16x8*)(qb + 32);
    }

    const ushort* Kbase = Kc + (size_t)bh * 2048 * 64;
    const ushort* Vbase = Vt + (size_t)bh * 64 * 2048;

    float lpa = 0.f, lpb = 0.f;
    f32x4 oa[4] = {}, ob[4] = {};

    for (int j0 = 0; j0 <= q0b; j0 += 64) {
        attn_step2g(Kbase + (size_t)j0 * 64, Vbase + j0,
                    qfA0, qfA1, qfB0, qfB1, lpa, lpb, oa, ob,
                    qwA, qwB, j0, q0a, q0b, col, g);
    }

    // epilogue: l[q=qw+col] lives replicated in the 4 g-lanes of each col group;
    // reduce across g (xor 16/32), then gather l for q=4g+r via lane shuffle.
    float la = lpa; la += __shfl_xor(la, 16); la += __shfl_xor(la, 32);
    float lb = lpb; lb += __shfl_xor(lb, 16); lb += __shfl_xor(lb, 32);
    const int b = bh >> 3, h = bh & 7;
    #pragma unroll
    for (int r = 0; r < 4; ++r) {
        const float inva = 1.f / __shfl(la, 4 * g + r);
        const float invb = 1.f / __shfl(lb, 4 * g + r);
        const size_t rowa = ((size_t)b * 2048 + qwA + 4 * g + r) * 512 + h * 64;
        const size_t rowb = ((size_t)b * 2048 + qwB + 4 * g + r) * 512 + h * 64;
        #pragma unroll
        for (int nt = 0; nt < 4; ++nt) {
            ctxb[rowa + nt * 16 + col] = f2bf(oa[nt][r] * inva);
            ctxb[rowb + nt * 16 + col] = f2bf(ob[nt][r] * invb);
        }
    }
}

// ---------------- LayerNorm(residual): out = LN(A + B1) * g + beta  (2-input)
// One WAVE per row (512 cols / 64 lanes = 8 elems/lane in two coalesced
// float4 passes), pure shfl_xor reduction -- no barriers.
template<int WRITE_BF16>
__global__ __launch_bounds__(256) void ln_residual(const float* __restrict__ A,
                            const float* __restrict__ B1,
                            const float* __restrict__ g, const float* __restrict__ beta,
                            float* __restrict__ out, ushort* __restrict__ outb) {
    const int lane = threadIdx.x & 63;
    const int row  = blockIdx.x * 4 + (threadIdx.x >> 6);
    const size_t base = (size_t)row * D_MODEL;
    const int c0 = lane * 4, c1 = 256 + lane * 4;

    float4 a0 = *(const float4*)&A[base + c0];
    float4 a1 = *(const float4*)&A[base + c1];
    float4 b0 = *(const float4*)&B1[base + c0];
    float4 b1 = *(const float4*)&B1[base + c1];
    float v0 = a0.x + b0.x, v1 = a0.y + b0.y, v2 = a0.z + b0.z, v3 = a0.w + b0.w;
    float v4 = a1.x + b1.x, v5 = a1.y + b1.y, v6 = a1.z + b1.z, v7 = a1.w + b1.w;

    float sum = ((v0 + v1) + (v2 + v3)) + ((v4 + v5) + (v6 + v7));
    #pragma unroll
    for (int off = 32; off; off >>= 1) sum += __shfl_xor(sum, off);
    const float mu = sum * (1.f / 512.f);

    float d0 = v0 - mu, d1 = v1 - mu, d2 = v2 - mu, d3 = v3 - mu;
    float d4 = v4 - mu, d5 = v5 - mu, d6 = v6 - mu, d7 = v7 - mu;
    float sq = ((d0 * d0 + d1 * d1) + (d2 * d2 + d3 * d3))
             + ((d4 * d4 + d5 * d5) + (d6 * d6 + d7 * d7));
    #pragma unroll
    for (int off = 32; off; off >>= 1) sq += __shfl_xor(sq, off);
    const float rs = rsqrtf(sq * (1.f / 512.f) + 1e-5f);

    float4 g0 = *(const float4*)&g[c0],    g1 = *(const float4*)&g[c1];
    float4 e0 = *(const float4*)&beta[c0], e1 = *(const float4*)&beta[c1];
    float4 r0, r1;
    r0.x = d0 * rs * g0.x + e0.x; r0.y = d1 * rs * g0.y + e0.y;
    r0.z = d2 * rs * g0.z + e0.z; r0.w = d3 * rs * g0.w + e0.w;
    r1.x = d4 * rs * g1.x + e1.x; r1.y = d5 * rs * g1.y + e1.y;
    r1.z = d6 * rs * g1.z + e1.z; r1.w = d7 * rs * g1.w + e1.w;
    *(float4*)&out[base + c0] = r0;
    *(float4*)&out[base + c1] = r1;
    if (WRITE_BF16) {
        ushort4 u0, u1;
        u0.x = f2bf(r0.x); u0.y = f2bf(r0.y); u0.z = f2bf(r0.z); u0.w = f2bf(r0.w);
        u1.x = f2bf(r1.x); u1.y = f2bf(r1.y); u1.z = f2bf(r1.z); u1.w = f2bf(r1.w);
        *(ushort4*)&outb[base + c0] = u0;
        *(ushort4*)&outb[base + c1] = u1;
    }
}

extern "C" void kernel_launch(void* const* d_in, const int* in_sizes, int n_in,
                              void* d_out, int out_size, void* d_ws, size_t ws_size,
                              hipStream_t stream) {
    const float* x    = (const float*)d_in[0];
    const float* Wqkv = (const float*)d_in[1];
    const float* bqkv = (const float*)d_in[2];
    const float* Wo   = (const float*)d_in[3];
    const float* bo   = (const float*)d_in[4];
    const float* W1   = (const float*)d_in[5];
    const float* b1   = (const float*)d_in[6];
    const float* W2   = (const float*)d_in[7];
    const float* b2   = (const float*)d_in[8];
    const float* g1   = (const float*)d_in[9];
    const float* bn1  = (const float*)d_in[10];
    const float* g2   = (const float*)d_in[11];
    const float* bn2  = (const float*)d_in[12];

    float* ws = (float*)d_ws;
    // time-multiplexed layout (floats):
    // [0,6291456)    Qcb/Kcb/Vtb (steps 1-2); ff1b [0,8388608) (steps 5-6)
    // [8388608,12582912)  ff2a (steps 6-7)
    // [12582912,16777216) attn_a (steps 3-4)
    // [16777216,20971520) ln1 fp32
    // [20971520,...) ctxb, ln1b, xb, Wqkvb, Wob, W1b, W2b (bf16)
    ushort* Qcb     = (ushort*)ws;
    ushort* Kcb     = (ushort*)(ws + 2097152);
    ushort* Vtb     = (ushort*)(ws + 4194304);
    ushort* ff1b    = (ushort*)ws;
    float*  ff2a    = ws + 8388608;
    float*  attn_a  = ws + 12582912;
    float*  ln1     = ws + 16777216;
    ushort* ctxb  = (ushort*)(ws + 20971520);
    ushort* ln1b  = (ushort*)(ws + 23068672);
    ushort* xb    = (ushort*)(ws + 25165824);
    ushort* Wqkvb = (ushort*)(ws + 27262976);
    float*  out   = (float*)d_out;
    ushort* W1b   = (ushort*)(ws + 27787264);
    ushort* W2b   = (ushort*)(ws + 28311552);
    ushort* Wob   = (ushort*)(ws + 27656192);

    const dim3 blk(256);

    // 0. fused casts (xb..W2b contiguous from xb)
    cast_all_bf16<<<dim3(7168), blk, 0, stream>>>(x, Wqkv, Wo, W1, W2, xb);

    // 1. QKV projection -> split Qc/Kc/Vt bf16 (128x128; 768 blk @3/CU exact)
    gemm_bt_mfma<2,0,128,128><<<dim3(1536/128, 8192/128), blk, 0, stream>>>(
        xb, Wqkvb, bqkv, nullptr, Qcb, Kcb, Vtb, TOKENS, 1536, 512, 512);
    // 2. MFMA flash attention (paired q-tiles, no-LDS direct-global) -> ctxb
    attn_mfma_kernel<<<dim3(512), blk, 0, stream>>>(Qcb, Kcb, Vtb, ctxb);
    // 3. output projection, full-K 64x128 tiles -> attn_a fp32 (+bias)
    gemm_bt_mfma<3,0,64,128><<<dim3(512/128, 8192/64), blk, 0, stream>>>(
        ctxb, Wob, bo, attn_a, nullptr, nullptr, nullptr, TOKENS, 512, 512, 512);
    // 4. LN1(x + attn_a) -> ln1 fp32 + ln1b bf16 (1 wave/row, 2048 blocks)
    ln_residual<1><<<dim3(TOKENS/4), blk, 0, stream>>>(x, attn_a, g1, bn1, ln1, ln1b);
    // 5. FF1 + ReLU -> ff1b bf16 [8192,2048]; 128x256 8-wave tile:
    //    512 blk @2/CU (72KB LDS, 16 waves/CU) = 1 exact round, 2x B-reuse
    gemm_bt_mfma<1,1,128,256><<<dim3(2048/256, 8192/128), dim3(512), 0, stream>>>(
        ln1b, W1b, b1, ff1b, nullptr, nullptr, nullptr, TOKENS, 2048, 512, 512);
    // 6. FF2, full-K 64x128 tiles -> ff2a fp32 (+bias)
    gemm_bt_mfma<3,0,64,128><<<dim3(512/128, 8192/64), blk, 0, stream>>>(
        ff1b, W2b, b2, ff2a, nullptr, nullptr, nullptr, TOKENS, 512, 2048, 2048);
    // 7. LN2(ln1 + ff2a) -> out (1 wave/row, 2048 blocks)
    ln_residual<0><<<dim3(TOKENS/4), blk, 0, stream>>>(ln1, ff2a, g2, bn2, out, nullptr);
}

// Round 13
// 235.108 us; speedup vs baseline: 1.3658x; 1.3658x over previous
//
#include <hip/hip_runtime.h>
#include <hip/hip_bf16.h>
#include <math.h>

#define D_MODEL 512
#define SEQ     2048
#define BATCH   4
#define NHEADS  8
#define HDIM    64
#define FFN     2048
#define TOKENS  (BATCH*SEQ)

typedef __attribute__((ext_vector_type(8))) short bf16x8;
typedef __attribute__((ext_vector_type(4))) float f32x4;
typedef __attribute__((ext_vector_type(4))) unsigned u32x4;

__device__ inline ushort f2bf(float f) {
    unsigned u = __builtin_bit_cast(unsigned, f);
    unsigned r = (u + 0x7fffu + ((u >> 16) & 1u)) >> 16;   // RNE
    return (ushort)r;
}

#define GLOAD_LDS16(g, l) __builtin_amdgcn_global_load_lds( \
    (const __attribute__((address_space(1))) void*)(g), \
    (__attribute__((address_space(3))) void*)(l), 16, 0, 0)

// ---------------- fused fp32 -> bf16 cast of x,Wqkv,Wo,W1,W2 (outputs contiguous)
__global__ void cast_all_bf16(const float* __restrict__ x, const float* __restrict__ Wqkv,
                              const float* __restrict__ Wo, const float* __restrict__ W1,
                              const float* __restrict__ W2, ushort* __restrict__ outbase) {
    const int i = blockIdx.x * blockDim.x + threadIdx.x;   // float4 index
    if (i >= 1835008) return;
    float4 v;
    if      (i < 1048576) v = ((const float4*)x)[i];
    else if (i < 1245184) v = ((const float4*)Wqkv)[i - 1048576];
    else if (i < 1310720) v = ((const float4*)Wo)[i - 1245184];
    else if (i < 1572864) v = ((const float4*)W1)[i - 1310720];
    else                  v = ((const float4*)W2)[i - 1572864];
    ushort4 o;
    o.x = f2bf(v.x); o.y = f2bf(v.y); o.z = f2bf(v.z); o.w = f2bf(v.w);
    ((ushort4*)outbase)[i] = o;
}

// ---------------- bf16 MFMA GEMM: C[M,N] = A[M,Kstride] @ W[N,Kstride]^T + bias
// MODE 1: bf16 out (+optional ReLU). MODE 2: qkv-split out. MODE 3: fp32 out
// with bias (full-K).
// Tile BM x BN; BN=128 -> 4 waves (2x2, 256 thr), BN=256 -> 8 waves (2x4,
// 512 thr). Wave output = (BM/2) x 64.
//   QKV: 128x128, 768 blk @3/CU (48KB) = 1 exact round
//   Wo/FF2: 64x128, 512 blk @4/CU (36KB) = 1 round
//   FF1: 128x256, 512 blk @2/CU (72KB, 16 waves/CU) = 1 exact round, 2x
//        B-reuse (round-9/10 A/B: ~5us gain vs 128-wide variants)
//
// Depth-3 K-pipeline with COUNTED vmcnt (T4): 3 LDS buffer pairs; per tile
// exactly one {s_waitcnt vmcnt(L); s_barrier}, L = loads/thread of one stage.
// Stage issued for t+2 right after the barrier stays in flight across TWO
// barriers. WAR safety: stage(t+2) overwrites the buffer computed at t-1;
// every wave passed barrier t only after finishing compute(t-1).
//
// XCD-grouped swizzle (T1): flat id f -> XCD f%8 owns gridDim.y/8
// consecutive m-panels x all n-blocks, n fastest.
//
// Bank-conflict swizzle (rule #21, verified conflicts->0): LDS slot
// (row, q16) holds global quarter q16 ^ ((row>>1)&3); LDS dest of
// global_load_lds stays LINEAR, global SOURCE column pre-swizzled, fragment
// reads XOR the same term.
// NO setprio in GEMM (catalog m190: null-to-negative without phase-split).
template<int MODE, int RELU, int BM, int BN>
__global__ __launch_bounds__(BN == 256 ? 512 : 256)
void gemm_bt_mfma(const ushort* __restrict__ A,
                  const ushort* __restrict__ W,
                  const float* __restrict__ bias,
                  void* __restrict__ CoutA,
                  ushort* __restrict__ Qc,
                  ushort* __restrict__ Kc,
                  ushort* __restrict__ Vt,
                  int M, int N, int Kstride, int Klen) {
    constexpr int NW    = (BN == 256) ? 8 : 4;   // waves per block
    constexpr int WC    = NW / 2;                // wave columns
    constexpr int MI    = BM / 32;               // m-fragments per wave
    constexpr int AROWS = BM / NW;               // A rows staged per wave (16/32)
    constexpr bool A2   = (AROWS == 32);         // second A load?
    __shared__ ushort Asb[3][BM * 32];
    __shared__ ushort Bsb[3][BN * 32];

    const int tid  = threadIdx.x;
    const int lane = tid & 63;
    const int wv   = tid >> 6;

    const int Gx = gridDim.x;
    const int f  = blockIdx.x + Gx * blockIdx.y;
    const int xc = f & 7;                 // XCD under %8 round-robin
    const int j  = f >> 3;
    const int ni = j % Gx;                // n fastest within the XCD
    const int mi = xc * (gridDim.y >> 3) + j / Gx;
    const int m0 = mi * BM;
    const int n0 = ni * BN;

    const int wm = (wv / WC) * (BM / 2);
    const int wn = (wv % WC) * 64;

    // staging: thread covers LDS slot row rA/rB, 16B-quarter (lane&3).
    // source column quarter = (lane&3) ^ s(row), s(row)=(row>>1)&3=(lane>>3)&3
    const int rA = wv * AROWS + (lane >> 2);
    const int rB = wv * 32 + (lane >> 2);
    const int cS = (((lane & 3) ^ ((lane >> 3) & 3)) * 8);
    const ushort* gA0 = A + (size_t)(m0 + rA) * Kstride + cS;
    const ushort* gA1 = gA0 + (size_t)16 * Kstride;     // used only if A2
    const ushort* gB0 = W + (size_t)(n0 + rB) * Kstride + cS;
    const ushort* gB1 = gB0 + (size_t)16 * Kstride;

    f32x4 acc[MI][4] = {};

    const int fr  = lane & 15;
    // fragment read: global quarter (lane>>4) of row r sits in LDS quarter
    // (lane>>4) ^ s(r); s(r) = (fr>>1)&3 independent of wm/i.
    const int fks = (((lane >> 4) ^ ((fr >> 1) & 3)) * 8);
    const int loA = wv * (AROWS * 32);    // this wave's A staging strip (ushorts)
    const int loB = wv * 1024;

#define STAGE(ab, bb) do { \
        GLOAD_LDS16(gA0, (ab) + loA); \
        if constexpr (A2) GLOAD_LDS16(gA1, (ab) + loA + 512); \
        GLOAD_LDS16(gB0, (bb) + loB); \
        GLOAD_LDS16(gB1, (bb) + loB + 512); \
        gA0 += 32; if constexpr (A2) gA1 += 32; \
        gB0 += 32; gB1 += 32; } while (0)

#define COMPUTE(ab, bb) do { \
        bf16x8 af_[MI], bf_[4]; \
        _Pragma("unroll") \
        for (int i_ = 0; i_ < MI; ++i_) \
            af_[i_] = *(const bf16x8*)((ab) + (wm + i_ * 16 + fr) * 32 + fks); \
        _Pragma("unroll") \
        for (int j_ = 0; j_ < 4; ++j_) \
            bf_[j_] = *(const bf16x8*)((bb) + (wn + j_ * 16 + fr) * 32 + fks); \
        _Pragma("unroll") \
        for (int i_ = 0; i_ < MI; ++i_) \
            _Pragma("unroll") \
            for (int j_ = 0; j_ < 4; ++j_) \
                acc[i_][j_] = __builtin_amdgcn_mfma_f32_16x16x32_bf16(af_[i_], bf_[j_], acc[i_][j_], 0, 0, 0); \
        } while (0)

#define PWAIT do { \
        if constexpr (A2) asm volatile("s_waitcnt vmcnt(4)" ::: "memory"); \
        else              asm volatile("s_waitcnt vmcnt(3)" ::: "memory"); \
        __builtin_amdgcn_s_barrier(); \
        __builtin_amdgcn_sched_barrier(0); } while (0)

    ushort *Ac = Asb[0], *An = Asb[1], *As = Asb[2];
    ushort *Bc = Bsb[0], *Bn = Bsb[1], *Bs = Bsb[2];

    STAGE(Ac, Bc);                        // tile 0
    STAGE(An, Bn);                        // tile 1
    const int ntiles = Klen >> 5;         // >= 8 for all our shapes
    for (int t = 0; t < ntiles - 1; ++t) {
        PWAIT;
        if (t + 2 < ntiles) STAGE(As, Bs);
        COMPUTE(Ac, Bc);
        ushort* tA = Ac; Ac = An; An = As; As = tA;
        ushort* tB = Bc; Bc = Bn; Bn = Bs; Bs = tB;
    }
    asm volatile("s_waitcnt vmcnt(0)" ::: "memory");
    __builtin_amdgcn_s_barrier();
    __builtin_amdgcn_sched_barrier(0);
    COMPUTE(Ac, Bc);

#undef STAGE
#undef COMPUTE
#undef PWAIT

    const int col  = lane & 15;
    const int rowq = (lane >> 4) * 4;
    #pragma unroll
    for (int i = 0; i < MI; ++i) {
        const int gm = m0 + wm + i * 16 + rowq;
        #pragma unroll
        for (int j2 = 0; j2 < 4; ++j2) {
            const int gn = n0 + wn + j2 * 16 + col;
            if (MODE == 2) {
                const float bv = bias[gn];
                const int seg = gn >> 9;
                const int h   = (gn >> 6) & 7;
                const int dd  = gn & 63;
                const int bb  = gm >> 11;
                const int ss  = gm & 2047;
                const int bh  = bb * 8 + h;
                if (seg == 2) {
                    ushort4 pk;
                    pk.x = f2bf(acc[i][j2][0] + bv);
                    pk.y = f2bf(acc[i][j2][1] + bv);
                    pk.z = f2bf(acc[i][j2][2] + bv);
                    pk.w = f2bf(acc[i][j2][3] + bv);
                    *(ushort4*)(Vt + ((size_t)bh * 64 + dd) * 2048 + ss) = pk;
                } else {
                    ushort* dst = (seg == 0 ? Qc : Kc) + ((size_t)bh * 2048 + ss) * 64 + dd;
                    #pragma unroll
                    for (int r = 0; r < 4; ++r)
                        dst[(size_t)r * 64] = f2bf(acc[i][j2][r] + bv);
                }
            } else if (MODE == 3) {
                float* dst = (float*)CoutA;
                const float bv = bias[gn];
                #pragma unroll
                for (int r = 0; r < 4; ++r)
                    dst[(size_t)(gm + r) * N + gn] = acc[i][j2][r] + bv;
            } else {
                const float bv = bias[gn];
                #pragma unroll
                for (int r = 0; r < 4; ++r) {
                    float v = acc[i][j2][r] + bv;
                    if (RELU) v = fmaxf(v, 0.f);
                    ((ushort*)CoutA)[(size_t)(gm + r) * N + gn] = f2bf(v);
                }
            }
        }
    }
}

// ---------------- one q-tile step, max-free online softmax, in-register P.
// QK^T computed SWAPPED: s = mfma(K, Q) -> lane (col,g) reg r holds
// S[k = j0 + nt*16 + 4g + r][q = qw + col].
// P->A-fragment transpose pure-register: cvt_pk pairs then permlane32/16
// swaps (lane-bit5/4 <-> reg-bit1); lane (col,g) ends holding
// P[q=qw+col][k=8g..] = the PV A-fragment.
// T5 setprio(1) around both MFMA clusters (catalog: +4-7% on attn).
__device__ __forceinline__ void attn_step(const ushort* __restrict__ Kb,
                                          const ushort* __restrict__ Vb,
                                          bf16x8 qf0, bf16x8 qf1,
                                          float& lp, f32x4 (&o)[4],
                                          int qw, int j0, bool diag,
                                          int col, int g, int c7) {
    f32x4 s[4] = {};
    __builtin_amdgcn_s_setprio(1);
    #pragma unroll
    for (int nt = 0; nt < 4; ++nt) {
        const int kr = nt * 16 + col;
        bf16x8 kf0 = *(const bf16x8*)(Kb + kr * 64 + (((g    ) ^ c7) * 8));
        bf16x8 kf1 = *(const bf16x8*)(Kb + kr * 64 + (((g + 4) ^ c7) * 8));
        s[nt] = __builtin_amdgcn_mfma_f32_16x16x32_bf16(kf0, qf0, s[nt], 0, 0, 0);
        s[nt] = __builtin_amdgcn_mfma_f32_16x16x32_bf16(kf1, qf1, s[nt], 0, 0, 0);
    }
    __builtin_amdgcn_s_setprio(0);

    if (diag) {
        #pragma unroll
        for (int nt = 0; nt < 4; ++nt)
            #pragma unroll
            for (int r = 0; r < 4; ++r)
                if ((j0 + nt * 16 + 4 * g + r) > (qw + col)) s[nt][r] = -INFINITY;
    }

    // p = exp(s/8); per-lane l partial is for the single q = qw+col
    unsigned W[8];
    #pragma unroll
    for (int nt = 0; nt < 4; ++nt) {
        float p0 = __expf(s[nt][0] * 0.125f);
        float p1 = __expf(s[nt][1] * 0.125f);
        float p2 = __expf(s[nt][2] * 0.125f);
        float p3 = __expf(s[nt][3] * 0.125f);
        lp += (p0 + p1) + (p2 + p3);
        asm("v_cvt_pk_bf16_f32 %0, %1, %2" : "=v"(W[2 * nt])     : "v"(p0), "v"(p1));
        asm("v_cvt_pk_bf16_f32 %0, %1, %2" : "=v"(W[2 * nt + 1]) : "v"(p2), "v"(p3));
    }
    // lane-bit5 <-> reg-bit1:  X'={X.lo,Y.lo}, Y'={X.hi,Y.hi}
    asm("v_permlane32_swap_b32 %0, %1" : "+v"(W[0]), "+v"(W[2]));
    asm("v_permlane32_swap_b32 %0, %1" : "+v"(W[1]), "+v"(W[3]));
    asm("v_permlane32_swap_b32 %0, %1" : "+v"(W[4]), "+v"(W[6]));
    asm("v_permlane32_swap_b32 %0, %1" : "+v"(W[5]), "+v"(W[7]));
    // lane-bit4 <-> reg-bit1 (within each 32-half): X'={X.r0,Y.r0}, Y'={X.r1,Y.r1}
    asm("v_permlane16_swap_b32 %0, %1" : "+v"(W[0]), "+v"(W[2]));
    asm("v_permlane16_swap_b32 %0, %1" : "+v"(W[1]), "+v"(W[3]));
    asm("v_permlane16_swap_b32 %0, %1" : "+v"(W[4]), "+v"(W[6]));
    asm("v_permlane16_swap_b32 %0, %1" : "+v"(W[5]), "+v"(W[7]));

    u32x4 wa = {W[0], W[1], W[2], W[3]};
    u32x4 wb = {W[4], W[5], W[6], W[7]};
    bf16x8 pf0 = __builtin_bit_cast(bf16x8, wa);
    bf16x8 pf1 = __builtin_bit_cast(bf16x8, wb);

    __builtin_amdgcn_s_setprio(1);
    #pragma unroll
    for (int nt = 0; nt < 4; ++nt) {
        const int vr = nt * 16 + col;
        bf16x8 vf0 = *(const bf16x8*)(Vb + vr * 64 + (((g    ) ^ c7) * 8));
        bf16x8 vf1 = *(const bf16x8*)(Vb + vr * 64 + (((g + 4) ^ c7) * 8));
        o[nt] = __builtin_amdgcn_mfma_f32_16x16x32_bf16(pf0, vf0, o[nt], 0, 0, 0);
        o[nt] = __builtin_amdgcn_mfma_f32_16x16x32_bf16(pf1, vf1, o[nt], 0, 0, 0);
    }
    __builtin_amdgcn_s_setprio(0);
}

// ---------------- MFMA flash attention, paired q-tiles, KVBLK=64 — the
// round-10 best-measured configuration (attn ~38us, total 239.4). Structural
// search CLOSED: split-K (worse, +traffic), unpair/occupancy x2 (flat),
// KVBLK=128 (bank conflicts), DMA+vmcnt(0) (drain stall), no-LDS direct
// global (121us -- LDS staging IS the coalescing transform: staging loads
// are coalesced 16B/lane; direct fragment reads scatter 64 lanes across 64
// rows). Reg-prefetch staging + per-tile barrier is the local optimum.
// XCD swizzle: all 16 pair-blocks of a bh on one XCD (K/V 2MB < 4MB L2).
__global__ __launch_bounds__(256, 4) void attn_mfma_kernel(const ushort* __restrict__ Qc,
                                                           const ushort* __restrict__ Kc,
                                                           const ushort* __restrict__ Vt,
                                                           ushort* __restrict__ ctxb) {
    __shared__ ushort Ks[2 * 64 * 64];
    __shared__ ushort Vs[2 * 64 * 64];

    const int tid  = threadIdx.x;
    const int lane = tid & 63;
    const int wv   = tid >> 6;
    const int idx  = blockIdx.x;                // 0..511
    const int bh   = (idx & 7) * 4 + (idx >> 7);
    const int pair = (idx >> 3) & 15;
    const int q0a  = pair * 64;
    const int q0b  = (31 - pair) * 64;
    const int qwA  = q0a + wv * 16;
    const int qwB  = q0b + wv * 16;

    const int col = lane & 15;
    const int g   = lane >> 4;
    const int c7  = col & 7;

    bf16x8 qfA0, qfA1, qfB0, qfB1;
    {
        const ushort* qa = Qc + ((size_t)bh * 2048 + qwA + col) * 64 + g * 8;
        qfA0 = *(const bf16x8*)qa;
        qfA1 = *(const bf16x8*)(qa + 32);
        const ushort* qb = Qc + ((size_t)bh * 2048 + qwB + col) * 64 + g * 8;
        qfB0 = *(const bf16x8*)qb;
        qfB1 = *(const bf16x8*)(qb + 32);
    }

    const int srow = tid >> 2;
    const int sch  = 2 * (tid & 3);
    const ushort* Kg = Kc + ((size_t)bh * 2048 + srow) * 64 + sch * 8;
    const ushort* Vg = Vt + ((size_t)bh * 64 + srow) * 2048 + sch * 8;
    const int ko0 = srow * 64 + (((sch    ) ^ (srow & 7)) * 8);
    const int ko1 = srow * 64 + (((sch + 1) ^ (srow & 7)) * 8);

    float lpa = 0.f, lpb = 0.f;
    f32x4 oa[4] = {}, ob[4] = {};

    bf16x8 pk0 = *(const bf16x8*)(Kg);
    bf16x8 pk1 = *(const bf16x8*)(Kg + 8);
    bf16x8 pv0 = *(const bf16x8*)(Vg);
    bf16x8 pv1 = *(const bf16x8*)(Vg + 8);

    for (int j0 = 0; j0 <= q0b; j0 += 64) {
        const int par = (j0 >> 6) & 1;
        ushort* Kb = Ks + par * 4096;
        ushort* Vb = Vs + par * 4096;
        *(bf16x8*)(Kb + ko0) = pk0; *(bf16x8*)(Kb + ko1) = pk1;
        *(bf16x8*)(Vb + ko0) = pv0; *(bf16x8*)(Vb + ko1) = pv1;
        __syncthreads();

        if (j0 < q0b) {
            pk0 = *(const bf16x8*)(Kg + (size_t)(j0 + 64) * 64);
            pk1 = *(const bf16x8*)(Kg + (size_t)(j0 + 64) * 64 + 8);
            pv0 = *(const bf16x8*)(Vg + j0 + 64);
            pv1 = *(const bf16x8*)(Vg + j0 + 72);
        }

        if (j0 <= q0a)
            attn_step(Kb, Vb, qfA0, qfA1, lpa, oa, qwA, j0, j0 == q0a, col, g, c7);
        attn_step(Kb, Vb, qfB0, qfB1, lpb, ob, qwB, j0, j0 == q0b, col, g, c7);
    }

    // epilogue: l[q=qw+col] lives replicated in the 4 g-lanes of each col group;
    // reduce across g (xor 16/32), then gather l for q=4g+r via lane shuffle.
    float la = lpa; la += __shfl_xor(la, 16); la += __shfl_xor(la, 32);
    float lb = lpb; lb += __shfl_xor(lb, 16); lb += __shfl_xor(lb, 32);
    const int b = bh >> 3, h = bh & 7;
    #pragma unroll
    for (int r = 0; r < 4; ++r) {
        const float inva = 1.f / __shfl(la, 4 * g + r);
        const float invb = 1.f / __shfl(lb, 4 * g + r);
        const size_t rowa = ((size_t)b * 2048 + qwA + 4 * g + r) * 512 + h * 64;
        const size_t rowb = ((size_t)b * 2048 + qwB + 4 * g + r) * 512 + h * 64;
        #pragma unroll
        for (int nt = 0; nt < 4; ++nt) {
            ctxb[rowa + nt * 16 + col] = f2bf(oa[nt][r] * inva);
            ctxb[rowb + nt * 16 + col] = f2bf(ob[nt][r] * invb);
        }
    }
}

// ---------------- LayerNorm(residual): out = LN(A + B1) * g + beta  (2-input)
// One WAVE per row (512 cols / 64 lanes = 8 elems/lane in two coalesced
// float4 passes), pure shfl_xor reduction -- no barriers. (Round-11
// isolated: neutral-to-slightly-positive vs block-per-row.)
template<int WRITE_BF16>
__global__ __launch_bounds__(256) void ln_residual(const float* __restrict__ A,
                            const float* __restrict__ B1,
                            const float* __restrict__ g, const float* __restrict__ beta,
                            float* __restrict__ out, ushort* __restrict__ outb) {
    const int lane = threadIdx.x & 63;
    const int row  = blockIdx.x * 4 + (threadIdx.x >> 6);
    const size_t base = (size_t)row * D_MODEL;
    const int c0 = lane * 4, c1 = 256 + lane * 4;

    float4 a0 = *(const float4*)&A[base + c0];
    float4 a1 = *(const float4*)&A[base + c1];
    float4 b0 = *(const float4*)&B1[base + c0];
    float4 b1 = *(const float4*)&B1[base + c1];
    float v0 = a0.x + b0.x, v1 = a0.y + b0.y, v2 = a0.z + b0.z, v3 = a0.w + b0.w;
    float v4 = a1.x + b1.x, v5 = a1.y + b1.y, v6 = a1.z + b1.z, v7 = a1.w + b1.w;

    float sum = ((v0 + v1) + (v2 + v3)) + ((v4 + v5) + (v6 + v7));
    #pragma unroll
    for (int off = 32; off; off >>= 1) sum += __shfl_xor(sum, off);
    const float mu = sum * (1.f / 512.f);

    float d0 = v0 - mu, d1 = v1 - mu, d2 = v2 - mu, d3 = v3 - mu;
    float d4 = v4 - mu, d5 = v5 - mu, d6 = v6 - mu, d7 = v7 - mu;
    float sq = ((d0 * d0 + d1 * d1) + (d2 * d2 + d3 * d3))
             + ((d4 * d4 + d5 * d5) + (d6 * d6 + d7 * d7));
    #pragma unroll
    for (int off = 32; off; off >>= 1) sq += __shfl_xor(sq, off);
    const float rs = rsqrtf(sq * (1.f / 512.f) + 1e-5f);

    float4 g0 = *(const float4*)&g[c0],    g1 = *(const float4*)&g[c1];
    float4 e0 = *(const float4*)&beta[c0], e1 = *(const float4*)&beta[c1];
    float4 r0, r1;
    r0.x = d0 * rs * g0.x + e0.x; r0.y = d1 * rs * g0.y + e0.y;
    r0.z = d2 * rs * g0.z + e0.z; r0.w = d3 * rs * g0.w + e0.w;
    r1.x = d4 * rs * g1.x + e1.x; r1.y = d5 * rs * g1.y + e1.y;
    r1.z = d6 * rs * g1.z + e1.z; r1.w = d7 * rs * g1.w + e1.w;
    *(float4*)&out[base + c0] = r0;
    *(float4*)&out[base + c1] = r1;
    if (WRITE_BF16) {
        ushort4 u0, u1;
        u0.x = f2bf(r0.x); u0.y = f2bf(r0.y); u0.z = f2bf(r0.z); u0.w = f2bf(r0.w);
        u1.x = f2bf(r1.x); u1.y = f2bf(r1.y); u1.z = f2bf(r1.z); u1.w = f2bf(r1.w);
        *(ushort4*)&outb[base + c0] = u0;
        *(ushort4*)&outb[base + c1] = u1;
    }
}

extern "C" void kernel_launch(void* const* d_in, const int* in_sizes, int n_in,
                              void* d_out, int out_size, void* d_ws, size_t ws_size,
                              hipStream_t stream) {
    const float* x    = (const float*)d_in[0];
    const float* Wqkv = (const float*)d_in[1];
    const float* bqkv = (const float*)d_in[2];
    const float* Wo   = (const float*)d_in[3];
    const float* bo   = (const float*)d_in[4];
    const float* W1   = (const float*)d_in[5];
    const float* b1   = (const float*)d_in[6];
    const float* W2   = (const float*)d_in[7];
    const float* b2   = (const float*)d_in[8];
    const float* g1   = (const float*)d_in[9];
    const float* bn1  = (const float*)d_in[10];
    const float* g2   = (const float*)d_in[11];
    const float* bn2  = (const float*)d_in[12];

    float* ws = (float*)d_ws;
    // time-multiplexed layout (floats):
    // [0,6291456)    Qcb/Kcb/Vtb (steps 1-2); ff1b [0,8388608) (steps 5-6)
    // [8388608,12582912)  ff2a (steps 6-7)
    // [12582912,16777216) attn_a (steps 3-4)
    // [16777216,20971520) ln1 fp32
    // [20971520,...) ctxb, ln1b, xb, Wqkvb, Wob, W1b, W2b (bf16)
    ushort* Qcb     = (ushort*)ws;
    ushort* Kcb     = (ushort*)(ws + 2097152);
    ushort* Vtb     = (ushort*)(ws + 4194304);
    ushort* ff1b    = (ushort*)ws;
    float*  ff2a    = ws + 8388608;
    float*  attn_a  = ws + 12582912;
    float*  ln1     = ws + 16777216;
    ushort* ctxb  = (ushort*)(ws + 20971520);
    ushort* ln1b  = (ushort*)(ws + 23068672);
    ushort* xb    = (ushort*)(ws + 25165824);
    ushort* Wqkvb = (ushort*)(ws + 27262976);
    float*  out   = (float*)d_out;
    ushort* W1b   = (ushort*)(ws + 27787264);
    ushort* W2b   = (ushort*)(ws + 28311552);
    ushort* Wob   = (ushort*)(ws + 27656192);

    const dim3 blk(256);

    // 0. fused casts (xb..W2b contiguous from xb)
    cast_all_bf16<<<dim3(7168), blk, 0, stream>>>(x, Wqkv, Wo, W1, W2, xb);

    // 1. QKV projection -> split Qc/Kc/Vt bf16 (128x128; 768 blk @3/CU exact)
    gemm_bt_mfma<2,0,128,128><<<dim3(1536/128, 8192/128), blk, 0, stream>>>(
        xb, Wqkvb, bqkv, nullptr, Qcb, Kcb, Vtb, TOKENS, 1536, 512, 512);
    // 2. MFMA flash attention (paired q-tiles, KVBLK=64, reg-prefetch) -> ctxb
    attn_mfma_kernel<<<dim3(512), blk, 0, stream>>>(Qcb, Kcb, Vtb, ctxb);
    // 3. output projection, full-K 64x128 tiles -> attn_a fp32 (+bias)
    gemm_bt_mfma<3,0,64,128><<<dim3(512/128, 8192/64), blk, 0, stream>>>(
        ctxb, Wob, bo, attn_a, nullptr, nullptr, nullptr, TOKENS, 512, 512, 512);
    // 4. LN1(x + attn_a) -> ln1 fp32 + ln1b bf16 (1 wave/row, 2048 blocks)
    ln_residual<1><<<dim3(TOKENS/4), blk, 0, stream>>>(x, attn_a, g1, bn1, ln1, ln1b);
    // 5. FF1 + ReLU -> ff1b bf16 [8192,2048]; 128x256 8-wave tile:
    //    512 blk @2/CU (72KB LDS, 16 waves/CU) = 1 exact round, 2x B-reuse
    gemm_bt_mfma<1,1,128,256><<<dim3(2048/256, 8192/128), dim3(512), 0, stream>>>(
        ln1b, W1b, b1, ff1b, nullptr, nullptr, nullptr, TOKENS, 2048, 512, 512);
    // 6. FF2, full-K 64x128 tiles -> ff2a fp32 (+bias)
    gemm_bt_mfma<3,0,64,128><<<dim3(512/128, 8192/64), blk, 0, stream>>>(
        ff1b, W2b, b2, ff2a, nullptr, nullptr, nullptr, TOKENS, 512, 2048, 2048);
    // 7. LN2(ln1 + ff2a) -> out (1 wave/row, 2048 blocks)
    ln_residual<0><<<dim3(TOKENS/4), blk, 0, stream>>>(ln1, ff2a, g2, bn2, out, nullptr);
}

// Round 14
// 234.385 us; speedup vs baseline: 1.3700x; 1.0031x over previous
//
#include <hip/hip_runtime.h>
#include <hip/hip_bf16.h>
#include <math.h>

#define D_MODEL 512
#define SEQ     2048
#define BATCH   4
#define NHEADS  8
#define HDIM    64
#define FFN     2048
#define TOKENS  (BATCH*SEQ)

typedef __attribute__((ext_vector_type(8))) short bf16x8;
typedef __attribute__((ext_vector_type(4))) float f32x4;
typedef __attribute__((ext_vector_type(4))) unsigned u32x4;

__device__ inline ushort f2bf(float f) {
    unsigned u = __builtin_bit_cast(unsigned, f);
    unsigned r = (u + 0x7fffu + ((u >> 16) & 1u)) >> 16;   // RNE
    return (ushort)r;
}

#define GLOAD_LDS16(g, l) __builtin_amdgcn_global_load_lds( \
    (const __attribute__((address_space(1))) void*)(g), \
    (__attribute__((address_space(3))) void*)(l), 16, 0, 0)

// ---------------- fused fp32 -> bf16 cast of x,Wqkv,Wo,W1,W2 (outputs contiguous)
__global__ void cast_all_bf16(const float* __restrict__ x, const float* __restrict__ Wqkv,
                              const float* __restrict__ Wo, const float* __restrict__ W1,
                              const float* __restrict__ W2, ushort* __restrict__ outbase) {
    const int i = blockIdx.x * blockDim.x + threadIdx.x;   // float4 index
    if (i >= 1835008) return;
    float4 v;
    if      (i < 1048576) v = ((const float4*)x)[i];
    else if (i < 1245184) v = ((const float4*)Wqkv)[i - 1048576];
    else if (i < 1310720) v = ((const float4*)Wo)[i - 1245184];
    else if (i < 1572864) v = ((const float4*)W1)[i - 1310720];
    else                  v = ((const float4*)W2)[i - 1572864];
    ushort4 o;
    o.x = f2bf(v.x); o.y = f2bf(v.y); o.z = f2bf(v.z); o.w = f2bf(v.w);
    ((ushort4*)outbase)[i] = o;
}

// ---------------- bf16 MFMA GEMM: C[M,N] = A[M,Kstride] @ W[N,Kstride]^T + bias
// MODE 1: bf16 out (+optional ReLU). MODE 2: qkv-split out. MODE 3: fp32 out
// with bias (full-K).
// Tile BM x BN; BN=128 -> 4 waves (2x2, 256 thr), BN=256 -> 8 waves (2x4,
// 512 thr). Wave output = (BM/2) x 64.
//   QKV: 128x128 depth-3, 768 blk @3/CU = 1 exact round
//   Wo/FF2: 64x128 DEPTH-4 (round-14): grid supplies only 2 blk/CU, and
//        48KB LDS still admits 3 -> depth-4 is residency-FREE; prefetch
//        cover grows 1 stage (~300cyc) -> 2 stages (~450+cyc) vs ~900cyc
//        HBM latency on FF2's streamed 32MB A.
//   FF1: 128x256 depth-3, 512 blk @2/CU (72KB) = 1 exact round
//
// Counted-vmcnt pipeline (T4), depth D: per tile one {s_waitcnt vmcnt(L);
// s_barrier}, L = (D-2)*loads_per_stage in the main loop (proves tile t
// landed while D-2 later stages stay in flight). Tail: the t=ntiles-2 wait
// MUST drop to vmcnt(loads) and t=ntiles-1 to vmcnt(0) (fewer stages
// outstanding -> bigger N no longer proves t landed). WAR safety: stage(t+D-1)
// overwrites the buffer computed at t-1; every wave passed barrier t only
// after finishing compute(t-1).
//
// XCD-grouped swizzle (T1): flat id f -> XCD f%8 owns gridDim.y/8
// consecutive m-panels x all n-blocks, n fastest.
//
// Bank-conflict swizzle (rule #21, verified conflicts->0): LDS slot
// (row, q16) holds global quarter q16 ^ ((row>>1)&3); LDS dest of
// global_load_lds stays LINEAR, global SOURCE column pre-swizzled, fragment
// reads XOR the same term.
// NO setprio in GEMM (catalog m190: null-to-negative without phase-split).
template<int MODE, int RELU, int BM, int BN>
__global__ __launch_bounds__(BN == 256 ? 512 : 256)
void gemm_bt_mfma(const ushort* __restrict__ A,
                  const ushort* __restrict__ W,
                  const float* __restrict__ bias,
                  void* __restrict__ CoutA,
                  ushort* __restrict__ Qc,
                  ushort* __restrict__ Kc,
                  ushort* __restrict__ Vt,
                  int M, int N, int Kstride, int Klen) {
    constexpr int NW    = (BN == 256) ? 8 : 4;   // waves per block
    constexpr int WC    = NW / 2;                // wave columns
    constexpr int MI    = BM / 32;               // m-fragments per wave
    constexpr int AROWS = BM / NW;               // A rows staged per wave (16/32)
    constexpr bool A2   = (AROWS == 32);         // second A load?
    constexpr int DEPTH = (BM == 64) ? 4 : 3;    // pipeline depth
    __shared__ ushort Asb[DEPTH][BM * 32];
    __shared__ ushort Bsb[DEPTH][BN * 32];

    const int tid  = threadIdx.x;
    const int lane = tid & 63;
    const int wv   = tid >> 6;

    const int Gx = gridDim.x;
    const int f  = blockIdx.x + Gx * blockIdx.y;
    const int xc = f & 7;                 // XCD under %8 round-robin
    const int j  = f >> 3;
    const int ni = j % Gx;                // n fastest within the XCD
    const int mi = xc * (gridDim.y >> 3) + j / Gx;
    const int m0 = mi * BM;
    const int n0 = ni * BN;

    const int wm = (wv / WC) * (BM / 2);
    const int wn = (wv % WC) * 64;

    // staging: thread covers LDS slot row rA/rB, 16B-quarter (lane&3).
    // source column quarter = (lane&3) ^ s(row), s(row)=(row>>1)&3=(lane>>3)&3
    const int rA = wv * AROWS + (lane >> 2);
    const int rB = wv * 32 + (lane >> 2);
    const int cS = (((lane & 3) ^ ((lane >> 3) & 3)) * 8);
    const ushort* gA0 = A + (size_t)(m0 + rA) * Kstride + cS;
    const ushort* gA1 = gA0 + (size_t)16 * Kstride;     // used only if A2
    const ushort* gB0 = W + (size_t)(n0 + rB) * Kstride + cS;
    const ushort* gB1 = gB0 + (size_t)16 * Kstride;

    f32x4 acc[MI][4] = {};

    const int fr  = lane & 15;
    // fragment read: global quarter (lane>>4) of row r sits in LDS quarter
    // (lane>>4) ^ s(r); s(r) = (fr>>1)&3 independent of wm/i.
    const int fks = (((lane >> 4) ^ ((fr >> 1) & 3)) * 8);
    const int loA = wv * (AROWS * 32);    // this wave's A staging strip (ushorts)
    const int loB = wv * 1024;

#define STAGE(ab, bb) do { \
        GLOAD_LDS16(gA0, (ab) + loA); \
        if constexpr (A2) GLOAD_LDS16(gA1, (ab) + loA + 512); \
        GLOAD_LDS16(gB0, (bb) + loB); \
        GLOAD_LDS16(gB1, (bb) + loB + 512); \
        gA0 += 32; if constexpr (A2) gA1 += 32; \
        gB0 += 32; gB1 += 32; } while (0)

#define COMPUTE(ab, bb) do { \
        bf16x8 af_[MI], bf_[4]; \
        _Pragma("unroll") \
        for (int i_ = 0; i_ < MI; ++i_) \
            af_[i_] = *(const bf16x8*)((ab) + (wm + i_ * 16 + fr) * 32 + fks); \
        _Pragma("unroll") \
        for (int j_ = 0; j_ < 4; ++j_) \
            bf_[j_] = *(const bf16x8*)((bb) + (wn + j_ * 16 + fr) * 32 + fks); \
        _Pragma("unroll") \
        for (int i_ = 0; i_ < MI; ++i_) \
            _Pragma("unroll") \
            for (int j_ = 0; j_ < 4; ++j_) \
                acc[i_][j_] = __builtin_amdgcn_mfma_f32_16x16x32_bf16(af_[i_], bf_[j_], acc[i_][j_], 0, 0, 0); \
        } while (0)

#define PBAR do { \
        __builtin_amdgcn_s_barrier(); \
        __builtin_amdgcn_sched_barrier(0); } while (0)

    const int ntiles = Klen >> 5;         // >= 16 for all our shapes

    if constexpr (DEPTH == 4) {
        // main-loop wait vmcnt(6) = 2 stages x 3 loads outstanding, tile t proven
        STAGE(Asb[0], Bsb[0]);
        STAGE(Asb[1], Bsb[1]);
        STAGE(Asb[2], Bsb[2]);
        for (int t = 0; t < ntiles - 2; ++t) {
            asm volatile("s_waitcnt vmcnt(6)" ::: "memory");
            PBAR;
            if (t + 3 < ntiles) STAGE(Asb[(t + 3) & 3], Bsb[(t + 3) & 3]);
            COMPUTE(Asb[t & 3], Bsb[t & 3]);
        }
        asm volatile("s_waitcnt vmcnt(3)" ::: "memory");
        PBAR;
        COMPUTE(Asb[(ntiles - 2) & 3], Bsb[(ntiles - 2) & 3]);
        asm volatile("s_waitcnt vmcnt(0)" ::: "memory");
        PBAR;
        COMPUTE(Asb[(ntiles - 1) & 3], Bsb[(ntiles - 1) & 3]);
    } else {
        ushort *Ac = Asb[0], *An = Asb[1], *As = Asb[2];
        ushort *Bc = Bsb[0], *Bn = Bsb[1], *Bs = Bsb[2];
        STAGE(Ac, Bc);                    // tile 0
        STAGE(An, Bn);                    // tile 1
        for (int t = 0; t < ntiles - 1; ++t) {
            if constexpr (A2) asm volatile("s_waitcnt vmcnt(4)" ::: "memory");
            else              asm volatile("s_waitcnt vmcnt(3)" ::: "memory");
            PBAR;
            if (t + 2 < ntiles) STAGE(As, Bs);
            COMPUTE(Ac, Bc);
            ushort* tA = Ac; Ac = An; An = As; As = tA;
            ushort* tB = Bc; Bc = Bn; Bn = Bs; Bs = tB;
        }
        asm volatile("s_waitcnt vmcnt(0)" ::: "memory");
        PBAR;
        COMPUTE(Ac, Bc);
    }

#undef STAGE
#undef COMPUTE
#undef PBAR

    const int col  = lane & 15;
    const int rowq = (lane >> 4) * 4;
    #pragma unroll
    for (int i = 0; i < MI; ++i) {
        const int gm = m0 + wm + i * 16 + rowq;
        #pragma unroll
        for (int j2 = 0; j2 < 4; ++j2) {
            const int gn = n0 + wn + j2 * 16 + col;
            if (MODE == 2) {
                const float bv = bias[gn];
                const int seg = gn >> 9;
                const int h   = (gn >> 6) & 7;
                const int dd  = gn & 63;
                const int bb  = gm >> 11;
                const int ss  = gm & 2047;
                const int bh  = bb * 8 + h;
                if (seg == 2) {
                    ushort4 pk;
                    pk.x = f2bf(acc[i][j2][0] + bv);
                    pk.y = f2bf(acc[i][j2][1] + bv);
                    pk.z = f2bf(acc[i][j2][2] + bv);
                    pk.w = f2bf(acc[i][j2][3] + bv);
                    *(ushort4*)(Vt + ((size_t)bh * 64 + dd) * 2048 + ss) = pk;
                } else {
                    ushort* dst = (seg == 0 ? Qc : Kc) + ((size_t)bh * 2048 + ss) * 64 + dd;
                    #pragma unroll
                    for (int r = 0; r < 4; ++r)
                        dst[(size_t)r * 64] = f2bf(acc[i][j2][r] + bv);
                }
            } else if (MODE == 3) {
                float* dst = (float*)CoutA;
                const float bv = bias[gn];
                #pragma unroll
                for (int r = 0; r < 4; ++r)
                    dst[(size_t)(gm + r) * N + gn] = acc[i][j2][r] + bv;
            } else {
                const float bv = bias[gn];
                #pragma unroll
                for (int r = 0; r < 4; ++r) {
                    float v = acc[i][j2][r] + bv;
                    if (RELU) v = fmaxf(v, 0.f);
                    ((ushort*)CoutA)[(size_t)(gm + r) * N + gn] = f2bf(v);
                }
            }
        }
    }
}

// ---------------- one q-tile step, max-free online softmax, in-register P.
// QK^T computed SWAPPED: s = mfma(K, Q) -> lane (col,g) reg r holds
// S[k = j0 + nt*16 + 4g + r][q = qw + col].
// P->A-fragment transpose pure-register: cvt_pk pairs then permlane32/16
// swaps (lane-bit5/4 <-> reg-bit1); lane (col,g) ends holding
// P[q=qw+col][k=8g..] = the PV A-fragment.
// T5 setprio(1) around both MFMA clusters (catalog: +4-7% on attn).
__device__ __forceinline__ void attn_step(const ushort* __restrict__ Kb,
                                          const ushort* __restrict__ Vb,
                                          bf16x8 qf0, bf16x8 qf1,
                                          float& lp, f32x4 (&o)[4],
                                          int qw, int j0, bool diag,
                                          int col, int g, int c7) {
    f32x4 s[4] = {};
    __builtin_amdgcn_s_setprio(1);
    #pragma unroll
    for (int nt = 0; nt < 4; ++nt) {
        const int kr = nt * 16 + col;
        bf16x8 kf0 = *(const bf16x8*)(Kb + kr * 64 + (((g    ) ^ c7) * 8));
        bf16x8 kf1 = *(const bf16x8*)(Kb + kr * 64 + (((g + 4) ^ c7) * 8));
        s[nt] = __builtin_amdgcn_mfma_f32_16x16x32_bf16(kf0, qf0, s[nt], 0, 0, 0);
        s[nt] = __builtin_amdgcn_mfma_f32_16x16x32_bf16(kf1, qf1, s[nt], 0, 0, 0);
    }
    __builtin_amdgcn_s_setprio(0);

    if (diag) {
        #pragma unroll
        for (int nt = 0; nt < 4; ++nt)
            #pragma unroll
            for (int r = 0; r < 4; ++r)
                if ((j0 + nt * 16 + 4 * g + r) > (qw + col)) s[nt][r] = -INFINITY;
    }

    // p = exp(s/8); per-lane l partial is for the single q = qw+col
    unsigned W[8];
    #pragma unroll
    for (int nt = 0; nt < 4; ++nt) {
        float p0 = __expf(s[nt][0] * 0.125f);
        float p1 = __expf(s[nt][1] * 0.125f);
        float p2 = __expf(s[nt][2] * 0.125f);
        float p3 = __expf(s[nt][3] * 0.125f);
        lp += (p0 + p1) + (p2 + p3);
        asm("v_cvt_pk_bf16_f32 %0, %1, %2" : "=v"(W[2 * nt])     : "v"(p0), "v"(p1));
        asm("v_cvt_pk_bf16_f32 %0, %1, %2" : "=v"(W[2 * nt + 1]) : "v"(p2), "v"(p3));
    }
    // lane-bit5 <-> reg-bit1:  X'={X.lo,Y.lo}, Y'={X.hi,Y.hi}
    asm("v_permlane32_swap_b32 %0, %1" : "+v"(W[0]), "+v"(W[2]));
    asm("v_permlane32_swap_b32 %0, %1" : "+v"(W[1]), "+v"(W[3]));
    asm("v_permlane32_swap_b32 %0, %1" : "+v"(W[4]), "+v"(W[6]));
    asm("v_permlane32_swap_b32 %0, %1" : "+v"(W[5]), "+v"(W[7]));
    // lane-bit4 <-> reg-bit1 (within each 32-half): X'={X.r0,Y.r0}, Y'={X.r1,Y.r1}
    asm("v_permlane16_swap_b32 %0, %1" : "+v"(W[0]), "+v"(W[2]));
    asm("v_permlane16_swap_b32 %0, %1" : "+v"(W[1]), "+v"(W[3]));
    asm("v_permlane16_swap_b32 %0, %1" : "+v"(W[4]), "+v"(W[6]));
    asm("v_permlane16_swap_b32 %0, %1" : "+v"(W[5]), "+v"(W[7]));

    u32x4 wa = {W[0], W[1], W[2], W[3]};
    u32x4 wb = {W[4], W[5], W[6], W[7]};
    bf16x8 pf0 = __builtin_bit_cast(bf16x8, wa);
    bf16x8 pf1 = __builtin_bit_cast(bf16x8, wb);

    __builtin_amdgcn_s_setprio(1);
    #pragma unroll
    for (int nt = 0; nt < 4; ++nt) {
        const int vr = nt * 16 + col;
        bf16x8 vf0 = *(const bf16x8*)(Vb + vr * 64 + (((g    ) ^ c7) * 8));
        bf16x8 vf1 = *(const bf16x8*)(Vb + vr * 64 + (((g + 4) ^ c7) * 8));
        o[nt] = __builtin_amdgcn_mfma_f32_16x16x32_bf16(pf0, vf0, o[nt], 0, 0, 0);
        o[nt] = __builtin_amdgcn_mfma_f32_16x16x32_bf16(pf1, vf1, o[nt], 0, 0, 0);
    }
    __builtin_amdgcn_s_setprio(0);
}

// ---------------- MFMA flash attention, paired q-tiles, KVBLK=64 — the
// round-10/13 best-measured configuration (attn ~38us). Structural search
// CLOSED: split-K (worse, +traffic), unpair/occupancy x2 (flat), KVBLK=128
// (bank conflicts), DMA+vmcnt(0) (drain stall), no-LDS direct global (121us
// -- LDS staging IS the coalescing transform). Reg-prefetch staging +
// per-tile barrier is the local optimum.
// XCD swizzle: all 16 pair-blocks of a bh on one XCD (K/V 2MB < 4MB L2).
__global__ __launch_bounds__(256, 4) void attn_mfma_kernel(const ushort* __restrict__ Qc,
                                                           const ushort* __restrict__ Kc,
                                                           const ushort* __restrict__ Vt,
                                                           ushort* __restrict__ ctxb) {
    __shared__ ushort Ks[2 * 64 * 64];
    __shared__ ushort Vs[2 * 64 * 64];

    const int tid  = threadIdx.x;
    const int lane = tid & 63;
    const int wv   = tid >> 6;
    const int idx  = blockIdx.x;                // 0..511
    const int bh   = (idx & 7) * 4 + (idx >> 7);
    const int pair = (idx >> 3) & 15;
    const int q0a  = pair * 64;
    const int q0b  = (31 - pair) * 64;
    const int qwA  = q0a + wv * 16;
    const int qwB  = q0b + wv * 16;

    const int col = lane & 15;
    const int g   = lane >> 4;
    const int c7  = col & 7;

    bf16x8 qfA0, qfA1, qfB0, qfB1;
    {
        const ushort* qa = Qc + ((size_t)bh * 2048 + qwA + col) * 64 + g * 8;
        qfA0 = *(const bf16x8*)qa;
        qfA1 = *(const bf16x8*)(qa + 32);
        const ushort* qb = Qc + ((size_t)bh * 2048 + qwB + col) * 64 + g * 8;
        qfB0 = *(const bf16x8*)qb;
        qfB1 = *(const bf16x8*)(qb + 32);
    }

    const int srow = tid >> 2;
    const int sch  = 2 * (tid & 3);
    const ushort* Kg = Kc + ((size_t)bh * 2048 + srow) * 64 + sch * 8;
    const ushort* Vg = Vt + ((size_t)bh * 64 + srow) * 2048 + sch * 8;
    const int ko0 = srow * 64 + (((sch    ) ^ (srow & 7)) * 8);
    const int ko1 = srow * 64 + (((sch + 1) ^ (srow & 7)) * 8);

    float lpa = 0.f, lpb = 0.f;
    f32x4 oa[4] = {}, ob[4] = {};

    bf16x8 pk0 = *(const bf16x8*)(Kg);
    bf16x8 pk1 = *(const bf16x8*)(Kg + 8);
    bf16x8 pv0 = *(const bf16x8*)(Vg);
    bf16x8 pv1 = *(const bf16x8*)(Vg + 8);

    for (int j0 = 0; j0 <= q0b; j0 += 64) {
        const int par = (j0 >> 6) & 1;
        ushort* Kb = Ks + par * 4096;
        ushort* Vb = Vs + par * 4096;
        *(bf16x8*)(Kb + ko0) = pk0; *(bf16x8*)(Kb + ko1) = pk1;
        *(bf16x8*)(Vb + ko0) = pv0; *(bf16x8*)(Vb + ko1) = pv1;
        __syncthreads();

        if (j0 < q0b) {
            pk0 = *(const bf16x8*)(Kg + (size_t)(j0 + 64) * 64);
            pk1 = *(const bf16x8*)(Kg + (size_t)(j0 + 64) * 64 + 8);
            pv0 = *(const bf16x8*)(Vg + j0 + 64);
            pv1 = *(const bf16x8*)(Vg + j0 + 72);
        }

        if (j0 <= q0a)
            attn_step(Kb, Vb, qfA0, qfA1, lpa, oa, qwA, j0, j0 == q0a, col, g, c7);
        attn_step(Kb, Vb, qfB0, qfB1, lpb, ob, qwB, j0, j0 == q0b, col, g, c7);
    }

    // epilogue: l[q=qw+col] lives replicated in the 4 g-lanes of each col group;
    // reduce across g (xor 16/32), then gather l for q=4g+r via lane shuffle.
    float la = lpa; la += __shfl_xor(la, 16); la += __shfl_xor(la, 32);
    float lb = lpb; lb += __shfl_xor(lb, 16); lb += __shfl_xor(lb, 32);
    const int b = bh >> 3, h = bh & 7;
    #pragma unroll
    for (int r = 0; r < 4; ++r) {
        const float inva = 1.f / __shfl(la, 4 * g + r);
        const float invb = 1.f / __shfl(lb, 4 * g + r);
        const size_t rowa = ((size_t)b * 2048 + qwA + 4 * g + r) * 512 + h * 64;
        const size_t rowb = ((size_t)b * 2048 + qwB + 4 * g + r) * 512 + h * 64;
        #pragma unroll
        for (int nt = 0; nt < 4; ++nt) {
            ctxb[rowa + nt * 16 + col] = f2bf(oa[nt][r] * inva);
            ctxb[rowb + nt * 16 + col] = f2bf(ob[nt][r] * invb);
        }
    }
}

// ---------------- LayerNorm(residual): out = LN(A + B1) * g + beta  (2-input)
// One WAVE per row (512 cols / 64 lanes = 8 elems/lane in two coalesced
// float4 passes), pure shfl_xor reduction -- no barriers.
template<int WRITE_BF16>
__global__ __launch_bounds__(256) void ln_residual(const float* __restrict__ A,
                            const float* __restrict__ B1,
                            const float* __restrict__ g, const float* __restrict__ beta,
                            float* __restrict__ out, ushort* __restrict__ outb) {
    const int lane = threadIdx.x & 63;
    const int row  = blockIdx.x * 4 + (threadIdx.x >> 6);
    const size_t base = (size_t)row * D_MODEL;
    const int c0 = lane * 4, c1 = 256 + lane * 4;

    float4 a0 = *(const float4*)&A[base + c0];
    float4 a1 = *(const float4*)&A[base + c1];
    float4 b0 = *(const float4*)&B1[base + c0];
    float4 b1 = *(const float4*)&B1[base + c1];
    float v0 = a0.x + b0.x, v1 = a0.y + b0.y, v2 = a0.z + b0.z, v3 = a0.w + b0.w;
    float v4 = a1.x + b1.x, v5 = a1.y + b1.y, v6 = a1.z + b1.z, v7 = a1.w + b1.w;

    float sum = ((v0 + v1) + (v2 + v3)) + ((v4 + v5) + (v6 + v7));
    #pragma unroll
    for (int off = 32; off; off >>= 1) sum += __shfl_xor(sum, off);
    const float mu = sum * (1.f / 512.f);

    float d0 = v0 - mu, d1 = v1 - mu, d2 = v2 - mu, d3 = v3 - mu;
    float d4 = v4 - mu, d5 = v5 - mu, d6 = v6 - mu, d7 = v7 - mu;
    float sq = ((d0 * d0 + d1 * d1) + (d2 * d2 + d3 * d3))
             + ((d4 * d4 + d5 * d5) + (d6 * d6 + d7 * d7));
    #pragma unroll
    for (int off = 32; off; off >>= 1) sq += __shfl_xor(sq, off);
    const float rs = rsqrtf(sq * (1.f / 512.f) + 1e-5f);

    float4 g0 = *(const float4*)&g[c0],    g1 = *(const float4*)&g[c1];
    float4 e0 = *(const float4*)&beta[c0], e1 = *(const float4*)&beta[c1];
    float4 r0, r1;
    r0.x = d0 * rs * g0.x + e0.x; r0.y = d1 * rs * g0.y + e0.y;
    r0.z = d2 * rs * g0.z + e0.z; r0.w = d3 * rs * g0.w + e0.w;
    r1.x = d4 * rs * g1.x + e1.x; r1.y = d5 * rs * g1.y + e1.y;
    r1.z = d6 * rs * g1.z + e1.z; r1.w = d7 * rs * g1.w + e1.w;
    *(float4*)&out[base + c0] = r0;
    *(float4*)&out[base + c1] = r1;
    if (WRITE_BF16) {
        ushort4 u0, u1;
        u0.x = f2bf(r0.x); u0.y = f2bf(r0.y); u0.z = f2bf(r0.z); u0.w = f2bf(r0.w);
        u1.x = f2bf(r1.x); u1.y = f2bf(r1.y); u1.z = f2bf(r1.z); u1.w = f2bf(r1.w);
        *(ushort4*)&outb[base + c0] = u0;
        *(ushort4*)&outb[base + c1] = u1;
    }
}

extern "C" void kernel_launch(void* const* d_in, const int* in_sizes, int n_in,
                              void* d_out, int out_size, void* d_ws, size_t ws_size,
                              hipStream_t stream) {
    const float* x    = (const float*)d_in[0];
    const float* Wqkv = (const float*)d_in[1];
    const float* bqkv = (const float*)d_in[2];
    const float* Wo   = (const float*)d_in[3];
    const float* bo   = (const float*)d_in[4];
    const float* W1   = (const float*)d_in[5];
    const float* b1   = (const float*)d_in[6];
    const float* W2   = (const float*)d_in[7];
    const float* b2   = (const float*)d_in[8];
    const float* g1   = (const float*)d_in[9];
    const float* bn1  = (const float*)d_in[10];
    const float* g2   = (const float*)d_in[11];
    const float* bn2  = (const float*)d_in[12];

    float* ws = (float*)d_ws;
    // time-multiplexed layout (floats):
    // [0,6291456)    Qcb/Kcb/Vtb (steps 1-2); ff1b [0,8388608) (steps 5-6)
    // [8388608,12582912)  ff2a (steps 6-7)
    // [12582912,16777216) attn_a (steps 3-4)
    // [16777216,20971520) ln1 fp32
    // [20971520,...) ctxb, ln1b, xb, Wqkvb, Wob, W1b, W2b (bf16)
    ushort* Qcb     = (ushort*)ws;
    ushort* Kcb     = (ushort*)(ws + 2097152);
    ushort* Vtb     = (ushort*)(ws + 4194304);
    ushort* ff1b    = (ushort*)ws;
    float*  ff2a    = ws + 8388608;
    float*  attn_a  = ws + 12582912;
    float*  ln1     = ws + 16777216;
    ushort* ctxb  = (ushort*)(ws + 20971520);
    ushort* ln1b  = (ushort*)(ws + 23068672);
    ushort* xb    = (ushort*)(ws + 25165824);
    ushort* Wqkvb = (ushort*)(ws + 27262976);
    float*  out   = (float*)d_out;
    ushort* W1b   = (ushort*)(ws + 27787264);
    ushort* W2b   = (ushort*)(ws + 28311552);
    ushort* Wob   = (ushort*)(ws + 27656192);

    const dim3 blk(256);

    // 0. fused casts (xb..W2b contiguous from xb)
    cast_all_bf16<<<dim3(7168), blk, 0, stream>>>(x, Wqkv, Wo, W1, W2, xb);

    // 1. QKV projection -> split Qc/Kc/Vt bf16 (128x128 depth-3; 768 blk @3/CU)
    gemm_bt_mfma<2,0,128,128><<<dim3(1536/128, 8192/128), blk, 0, stream>>>(
        xb, Wqkvb, bqkv, nullptr, Qcb, Kcb, Vtb, TOKENS, 1536, 512, 512);
    // 2. MFMA flash attention (paired q-tiles, KVBLK=64, reg-prefetch) -> ctxb
    attn_mfma_kernel<<<dim3(512), blk, 0, stream>>>(Qcb, Kcb, Vtb, ctxb);
    // 3. output projection, full-K 64x128 depth-4 -> attn_a fp32 (+bias)
    gemm_bt_mfma<3,0,64,128><<<dim3(512/128, 8192/64), blk, 0, stream>>>(
        ctxb, Wob, bo, attn_a, nullptr, nullptr, nullptr, TOKENS, 512, 512, 512);
    // 4. LN1(x + attn_a) -> ln1 fp32 + ln1b bf16 (1 wave/row, 2048 blocks)
    ln_residual<1><<<dim3(TOKENS/4), blk, 0, stream>>>(x, attn_a, g1, bn1, ln1, ln1b);
    // 5. FF1 + ReLU -> ff1b bf16 [8192,2048]; 128x256 8-wave depth-3:
    //    512 blk @2/CU (72KB LDS, 16 waves/CU) = 1 exact round, 2x B-reuse
    gemm_bt_mfma<1,1,128,256><<<dim3(2048/256, 8192/128), dim3(512), 0, stream>>>(
        ln1b, W1b, b1, ff1b, nullptr, nullptr, nullptr, TOKENS, 2048, 512, 512);
    // 6. FF2, full-K 64x128 depth-4 -> ff2a fp32 (+bias)
    gemm_bt_mfma<3,0,64,128><<<dim3(512/128, 8192/64), blk, 0, stream>>>(
        ff1b, W2b, b2, ff2a, nullptr, nullptr, nullptr, TOKENS, 512, 2048, 2048);
    // 7. LN2(ln1 + ff2a) -> out (1 wave/row, 2048 blocks)
    ln_residual<0><<<dim3(TOKENS/4), blk, 0, stream>>>(ln1, ff2a, g2, bn2, out, nullptr);
}

// Round 15
// 231.327 us; speedup vs baseline: 1.3881x; 1.0132x over previous
//
#include <hip/hip_runtime.h>
#include <hip/hip_bf16.h>
#include <math.h>

#define D_MODEL 512
#define SEQ     2048
#define BATCH   4
#define NHEADS  8
#define HDIM    64
#define FFN     2048
#define TOKENS  (BATCH*SEQ)

typedef __attribute__((ext_vector_type(8))) short bf16x8;
typedef __attribute__((ext_vector_type(4))) float f32x4;
typedef __attribute__((ext_vector_type(4))) unsigned u32x4;

__device__ inline ushort f2bf(float f) {
    unsigned u = __builtin_bit_cast(unsigned, f);
    unsigned r = (u + 0x7fffu + ((u >> 16) & 1u)) >> 16;   // RNE
    return (ushort)r;
}

#define GLOAD_LDS16(g, l) __builtin_amdgcn_global_load_lds( \
    (const __attribute__((address_space(1))) void*)(g), \
    (__attribute__((address_space(3))) void*)(l), 16, 0, 0)

// ---------------- fused fp32 -> bf16 cast of x,Wqkv,Wo,W1,W2 (outputs contiguous)
__global__ void cast_all_bf16(const float* __restrict__ x, const float* __restrict__ Wqkv,
                              const float* __restrict__ Wo, const float* __restrict__ W1,
                              const float* __restrict__ W2, ushort* __restrict__ outbase) {
    const int i = blockIdx.x * blockDim.x + threadIdx.x;   // float4 index
    if (i >= 1835008) return;
    float4 v;
    if      (i < 1048576) v = ((const float4*)x)[i];
    else if (i < 1245184) v = ((const float4*)Wqkv)[i - 1048576];
    else if (i < 1310720) v = ((const float4*)Wo)[i - 1245184];
    else if (i < 1572864) v = ((const float4*)W1)[i - 1310720];
    else                  v = ((const float4*)W2)[i - 1572864];
    ushort4 o;
    o.x = f2bf(v.x); o.y = f2bf(v.y); o.z = f2bf(v.z); o.w = f2bf(v.w);
    ((ushort4*)outbase)[i] = o;
}

// ---------------- bf16 MFMA GEMM: C[M,N] = A[M,Kstride] @ W[N,Kstride]^T + bias
// MODE 1: bf16 out (+optional ReLU). MODE 2: qkv-split out. MODE 3: fp32 out
// with bias (full-K).
// Tile BM x BN; BN=128 -> 4 waves (2x2, 256 thr), BN=256 -> 8 waves (2x4,
// 512 thr). Wave output = (BM/2) x 64.
//   QKV: 128x128 depth-3, 768 blk @3/CU = 1 exact round
//   Wo/FF2: 64x128 DEPTH-6, GROUP-OF-2 (round-15): compute TWO K-tiles per
//        {wait; barrier}. 6 BK=32 buffers = 72KB -> still 2 blk/CU (= grid
//        supply; residency-free). Barrier count halves (FF2 64->32), MFMA
//        per barrier doubles to 16/wave -- attacks the barrier-cadence cost
//        (depth-4 only extended prefetch cover, measured ~neutral).
//        Group g: wait vmcnt(6) (stages for tiles 2g+2,2g+3 = 6 loads stay
//        in flight; FIFO proves tiles 2g,2g+1 landed), barrier, issue
//        stages 2g+4,2g+5, compute both tiles. WAR: stage(2g+4) overwrites
//        buf[(2g+4)%6] last computed at group g-1; every wave passed
//        barrier g only after finishing group g-1.
//   FF1: 128x256 depth-3, 512 blk @2/CU (72KB) = 1 exact round
//
// XCD-grouped swizzle (T1): flat id f -> XCD f%8 owns gridDim.y/8
// consecutive m-panels x all n-blocks, n fastest.
//
// Bank-conflict swizzle (rule #21, verified conflicts->0): LDS slot
// (row, q16) holds global quarter q16 ^ ((row>>1)&3); LDS dest of
// global_load_lds stays LINEAR, global SOURCE column pre-swizzled, fragment
// reads XOR the same term.
// NO setprio in GEMM (catalog m190: null-to-negative without phase-split).
template<int MODE, int RELU, int BM, int BN>
__global__ __launch_bounds__(BN == 256 ? 512 : 256)
void gemm_bt_mfma(const ushort* __restrict__ A,
                  const ushort* __restrict__ W,
                  const float* __restrict__ bias,
                  void* __restrict__ CoutA,
                  ushort* __restrict__ Qc,
                  ushort* __restrict__ Kc,
                  ushort* __restrict__ Vt,
                  int M, int N, int Kstride, int Klen) {
    constexpr int NW    = (BN == 256) ? 8 : 4;   // waves per block
    constexpr int WC    = NW / 2;                // wave columns
    constexpr int MI    = BM / 32;               // m-fragments per wave
    constexpr int AROWS = BM / NW;               // A rows staged per wave (16/32)
    constexpr bool A2   = (AROWS == 32);         // second A load?
    constexpr int DEPTH = (BM == 64) ? 6 : 3;    // pipeline depth
    __shared__ ushort Asb[DEPTH][BM * 32];
    __shared__ ushort Bsb[DEPTH][BN * 32];

    const int tid  = threadIdx.x;
    const int lane = tid & 63;
    const int wv   = tid >> 6;

    const int Gx = gridDim.x;
    const int f  = blockIdx.x + Gx * blockIdx.y;
    const int xc = f & 7;                 // XCD under %8 round-robin
    const int j  = f >> 3;
    const int ni = j % Gx;                // n fastest within the XCD
    const int mi = xc * (gridDim.y >> 3) + j / Gx;
    const int m0 = mi * BM;
    const int n0 = ni * BN;

    const int wm = (wv / WC) * (BM / 2);
    const int wn = (wv % WC) * 64;

    // staging: thread covers LDS slot row rA/rB, 16B-quarter (lane&3).
    // source column quarter = (lane&3) ^ s(row), s(row)=(row>>1)&3=(lane>>3)&3
    const int rA = wv * AROWS + (lane >> 2);
    const int rB = wv * 32 + (lane >> 2);
    const int cS = (((lane & 3) ^ ((lane >> 3) & 3)) * 8);
    const ushort* gA0 = A + (size_t)(m0 + rA) * Kstride + cS;
    const ushort* gA1 = gA0 + (size_t)16 * Kstride;     // used only if A2
    const ushort* gB0 = W + (size_t)(n0 + rB) * Kstride + cS;
    const ushort* gB1 = gB0 + (size_t)16 * Kstride;

    f32x4 acc[MI][4] = {};

    const int fr  = lane & 15;
    // fragment read: global quarter (lane>>4) of row r sits in LDS quarter
    // (lane>>4) ^ s(r); s(r) = (fr>>1)&3 independent of wm/i.
    const int fks = (((lane >> 4) ^ ((fr >> 1) & 3)) * 8);
    const int loA = wv * (AROWS * 32);    // this wave's A staging strip (ushorts)
    const int loB = wv * 1024;

#define STAGE(ab, bb) do { \
        GLOAD_LDS16(gA0, (ab) + loA); \
        if constexpr (A2) GLOAD_LDS16(gA1, (ab) + loA + 512); \
        GLOAD_LDS16(gB0, (bb) + loB); \
        GLOAD_LDS16(gB1, (bb) + loB + 512); \
        gA0 += 32; if constexpr (A2) gA1 += 32; \
        gB0 += 32; gB1 += 32; } while (0)

#define COMPUTE(ab, bb) do { \
        bf16x8 af_[MI], bf_[4]; \
        _Pragma("unroll") \
        for (int i_ = 0; i_ < MI; ++i_) \
            af_[i_] = *(const bf16x8*)((ab) + (wm + i_ * 16 + fr) * 32 + fks); \
        _Pragma("unroll") \
        for (int j_ = 0; j_ < 4; ++j_) \
            bf_[j_] = *(const bf16x8*)((bb) + (wn + j_ * 16 + fr) * 32 + fks); \
        _Pragma("unroll") \
        for (int i_ = 0; i_ < MI; ++i_) \
            _Pragma("unroll") \
            for (int j_ = 0; j_ < 4; ++j_) \
                acc[i_][j_] = __builtin_amdgcn_mfma_f32_16x16x32_bf16(af_[i_], bf_[j_], acc[i_][j_], 0, 0, 0); \
        } while (0)

#define PBAR do { \
        __builtin_amdgcn_s_barrier(); \
        __builtin_amdgcn_sched_barrier(0); } while (0)

    const int ntiles = Klen >> 5;         // >= 16 for all our shapes (even)

    if constexpr (DEPTH == 6) {
        // group-of-2 tiles per barrier; see header comment for vmcnt/WAR proof
        STAGE(Asb[0], Bsb[0]);
        STAGE(Asb[1], Bsb[1]);
        STAGE(Asb[2], Bsb[2]);
        STAGE(Asb[3], Bsb[3]);
        const int ngroups = ntiles >> 1;
        int b0 = 0;                       // buffer of group's first tile (0/2/4)
        for (int gi = 0; gi < ngroups; ++gi) {
            if (gi == ngroups - 1) asm volatile("s_waitcnt vmcnt(0)" ::: "memory");
            else                   asm volatile("s_waitcnt vmcnt(6)" ::: "memory");
            PBAR;
            if (2 * gi + 4 < ntiles) {
                const int bs = (b0 >= 2) ? b0 - 2 : b0 + 4;   // (b0+4)%6
                STAGE(Asb[bs], Bsb[bs]);
                STAGE(Asb[bs + 1], Bsb[bs + 1]);
            }
            COMPUTE(Asb[b0], Bsb[b0]);
            COMPUTE(Asb[b0 + 1], Bsb[b0 + 1]);
            b0 += 2; if (b0 >= 6) b0 = 0;
        }
    } else {
        ushort *Ac = Asb[0], *An = Asb[1], *As = Asb[2];
        ushort *Bc = Bsb[0], *Bn = Bsb[1], *Bs = Bsb[2];
        STAGE(Ac, Bc);                    // tile 0
        STAGE(An, Bn);                    // tile 1
        for (int t = 0; t < ntiles - 1; ++t) {
            if constexpr (A2) asm volatile("s_waitcnt vmcnt(4)" ::: "memory");
            else              asm volatile("s_waitcnt vmcnt(3)" ::: "memory");
            PBAR;
            if (t + 2 < ntiles) STAGE(As, Bs);
            COMPUTE(Ac, Bc);
            ushort* tA = Ac; Ac = An; An = As; As = tA;
            ushort* tB = Bc; Bc = Bn; Bn = Bs; Bs = tB;
        }
        asm volatile("s_waitcnt vmcnt(0)" ::: "memory");
        PBAR;
        COMPUTE(Ac, Bc);
    }

#undef STAGE
#undef COMPUTE
#undef PBAR

    const int col  = lane & 15;
    const int rowq = (lane >> 4) * 4;
    #pragma unroll
    for (int i = 0; i < MI; ++i) {
        const int gm = m0 + wm + i * 16 + rowq;
        #pragma unroll
        for (int j2 = 0; j2 < 4; ++j2) {
            const int gn = n0 + wn + j2 * 16 + col;
            if (MODE == 2) {
                const float bv = bias[gn];
                const int seg = gn >> 9;
                const int h   = (gn >> 6) & 7;
                const int dd  = gn & 63;
                const int bb  = gm >> 11;
                const int ss  = gm & 2047;
                const int bh  = bb * 8 + h;
                if (seg == 2) {
                    ushort4 pk;
                    pk.x = f2bf(acc[i][j2][0] + bv);
                    pk.y = f2bf(acc[i][j2][1] + bv);
                    pk.z = f2bf(acc[i][j2][2] + bv);
                    pk.w = f2bf(acc[i][j2][3] + bv);
                    *(ushort4*)(Vt + ((size_t)bh * 64 + dd) * 2048 + ss) = pk;
                } else {
                    ushort* dst = (seg == 0 ? Qc : Kc) + ((size_t)bh * 2048 + ss) * 64 + dd;
                    #pragma unroll
                    for (int r = 0; r < 4; ++r)
                        dst[(size_t)r * 64] = f2bf(acc[i][j2][r] + bv);
                }
            } else if (MODE == 3) {
                float* dst = (float*)CoutA;
                const float bv = bias[gn];
                #pragma unroll
                for (int r = 0; r < 4; ++r)
                    dst[(size_t)(gm + r) * N + gn] = acc[i][j2][r] + bv;
            } else {
                const float bv = bias[gn];
                #pragma unroll
                for (int r = 0; r < 4; ++r) {
                    float v = acc[i][j2][r] + bv;
                    if (RELU) v = fmaxf(v, 0.f);
                    ((ushort*)CoutA)[(size_t)(gm + r) * N + gn] = f2bf(v);
                }
            }
        }
    }
}

// ---------------- one q-tile step, max-free online softmax, in-register P.
// QK^T computed SWAPPED: s = mfma(K, Q) -> lane (col,g) reg r holds
// S[k = j0 + nt*16 + 4g + r][q = qw + col].
// P->A-fragment transpose pure-register: cvt_pk pairs then permlane32/16
// swaps (lane-bit5/4 <-> reg-bit1); lane (col,g) ends holding
// P[q=qw+col][k=8g..] = the PV A-fragment.
// T5 setprio(1) around both MFMA clusters (catalog: +4-7% on attn).
__device__ __forceinline__ void attn_step(const ushort* __restrict__ Kb,
                                          const ushort* __restrict__ Vb,
                                          bf16x8 qf0, bf16x8 qf1,
                                          float& lp, f32x4 (&o)[4],
                                          int qw, int j0, bool diag,
                                          int col, int g, int c7) {
    f32x4 s[4] = {};
    __builtin_amdgcn_s_setprio(1);
    #pragma unroll
    for (int nt = 0; nt < 4; ++nt) {
        const int kr = nt * 16 + col;
        bf16x8 kf0 = *(const bf16x8*)(Kb + kr * 64 + (((g    ) ^ c7) * 8));
        bf16x8 kf1 = *(const bf16x8*)(Kb + kr * 64 + (((g + 4) ^ c7) * 8));
        s[nt] = __builtin_amdgcn_mfma_f32_16x16x32_bf16(kf0, qf0, s[nt], 0, 0, 0);
        s[nt] = __builtin_amdgcn_mfma_f32_16x16x32_bf16(kf1, qf1, s[nt], 0, 0, 0);
    }
    __builtin_amdgcn_s_setprio(0);

    if (diag) {
        #pragma unroll
        for (int nt = 0; nt < 4; ++nt)
            #pragma unroll
            for (int r = 0; r < 4; ++r)
                if ((j0 + nt * 16 + 4 * g + r) > (qw + col)) s[nt][r] = -INFINITY;
    }

    // p = exp(s/8); per-lane l partial is for the single q = qw+col
    unsigned W[8];
    #pragma unroll
    for (int nt = 0; nt < 4; ++nt) {
        float p0 = __expf(s[nt][0] * 0.125f);
        float p1 = __expf(s[nt][1] * 0.125f);
        float p2 = __expf(s[nt][2] * 0.125f);
        float p3 = __expf(s[nt][3] * 0.125f);
        lp += (p0 + p1) + (p2 + p3);
        asm("v_cvt_pk_bf16_f32 %0, %1, %2" : "=v"(W[2 * nt])     : "v"(p0), "v"(p1));
        asm("v_cvt_pk_bf16_f32 %0, %1, %2" : "=v"(W[2 * nt + 1]) : "v"(p2), "v"(p3));
    }
    // lane-bit5 <-> reg-bit1:  X'={X.lo,Y.lo}, Y'={X.hi,Y.hi}
    asm("v_permlane32_swap_b32 %0, %1" : "+v"(W[0]), "+v"(W[2]));
    asm("v_permlane32_swap_b32 %0, %1" : "+v"(W[1]), "+v"(W[3]));
    asm("v_permlane32_swap_b32 %0, %1" : "+v"(W[4]), "+v"(W[6]));
    asm("v_permlane32_swap_b32 %0, %1" : "+v"(W[5]), "+v"(W[7]));
    // lane-bit4 <-> reg-bit1 (within each 32-half): X'={X.r0,Y.r0}, Y'={X.r1,Y.r1}
    asm("v_permlane16_swap_b32 %0, %1" : "+v"(W[0]), "+v"(W[2]));
    asm("v_permlane16_swap_b32 %0, %1" : "+v"(W[1]), "+v"(W[3]));
    asm("v_permlane16_swap_b32 %0, %1" : "+v"(W[4]), "+v"(W[6]));
    asm("v_permlane16_swap_b32 %0, %1" : "+v"(W[5]), "+v"(W[7]));

    u32x4 wa = {W[0], W[1], W[2], W[3]};
    u32x4 wb = {W[4], W[5], W[6], W[7]};
    bf16x8 pf0 = __builtin_bit_cast(bf16x8, wa);
    bf16x8 pf1 = __builtin_bit_cast(bf16x8, wb);

    __builtin_amdgcn_s_setprio(1);
    #pragma unroll
    for (int nt = 0; nt < 4; ++nt) {
        const int vr = nt * 16 + col;
        bf16x8 vf0 = *(const bf16x8*)(Vb + vr * 64 + (((g    ) ^ c7) * 8));
        bf16x8 vf1 = *(const bf16x8*)(Vb + vr * 64 + (((g + 4) ^ c7) * 8));
        o[nt] = __builtin_amdgcn_mfma_f32_16x16x32_bf16(pf0, vf0, o[nt], 0, 0, 0);
        o[nt] = __builtin_amdgcn_mfma_f32_16x16x32_bf16(pf1, vf1, o[nt], 0, 0, 0);
    }
    __builtin_amdgcn_s_setprio(0);
}

// ---------------- MFMA flash attention, paired q-tiles, KVBLK=64 — the
// round-10/13 best-measured configuration (attn ~38us). Structural search
// CLOSED: split-K (worse, +traffic), unpair/occupancy x2 (flat), KVBLK=128
// (bank conflicts), DMA+vmcnt(0) (drain stall), no-LDS direct global (121us
// -- LDS staging IS the coalescing transform). Reg-prefetch staging +
// per-tile barrier is the local optimum.
// XCD swizzle: all 16 pair-blocks of a bh on one XCD (K/V 2MB < 4MB L2).
__global__ __launch_bounds__(256, 4) void attn_mfma_kernel(const ushort* __restrict__ Qc,
                                                           const ushort* __restrict__ Kc,
                                                           const ushort* __restrict__ Vt,
                                                           ushort* __restrict__ ctxb) {
    __shared__ ushort Ks[2 * 64 * 64];
    __shared__ ushort Vs[2 * 64 * 64];

    const int tid  = threadIdx.x;
    const int lane = tid & 63;
    const int wv   = tid >> 6;
    const int idx  = blockIdx.x;                // 0..511
    const int bh   = (idx & 7) * 4 + (idx >> 7);
    const int pair = (idx >> 3) & 15;
    const int q0a  = pair * 64;
    const int q0b  = (31 - pair) * 64;
    const int qwA  = q0a + wv * 16;
    const int qwB  = q0b + wv * 16;

    const int col = lane & 15;
    const int g   = lane >> 4;
    const int c7  = col & 7;

    bf16x8 qfA0, qfA1, qfB0, qfB1;
    {
        const ushort* qa = Qc + ((size_t)bh * 2048 + qwA + col) * 64 + g * 8;
        qfA0 = *(const bf16x8*)qa;
        qfA1 = *(const bf16x8*)(qa + 32);
        const ushort* qb = Qc + ((size_t)bh * 2048 + qwB + col) * 64 + g * 8;
        qfB0 = *(const bf16x8*)qb;
        qfB1 = *(const bf16x8*)(qb + 32);
    }

    const int srow = tid >> 2;
    const int sch  = 2 * (tid & 3);
    const ushort* Kg = Kc + ((size_t)bh * 2048 + srow) * 64 + sch * 8;
    const ushort* Vg = Vt + ((size_t)bh * 64 + srow) * 2048 + sch * 8;
    const int ko0 = srow * 64 + (((sch    ) ^ (srow & 7)) * 8);
    const int ko1 = srow * 64 + (((sch + 1) ^ (srow & 7)) * 8);

    float lpa = 0.f, lpb = 0.f;
    f32x4 oa[4] = {}, ob[4] = {};

    bf16x8 pk0 = *(const bf16x8*)(Kg);
    bf16x8 pk1 = *(const bf16x8*)(Kg + 8);
    bf16x8 pv0 = *(const bf16x8*)(Vg);
    bf16x8 pv1 = *(const bf16x8*)(Vg + 8);

    for (int j0 = 0; j0 <= q0b; j0 += 64) {
        const int par = (j0 >> 6) & 1;
        ushort* Kb = Ks + par * 4096;
        ushort* Vb = Vs + par * 4096;
        *(bf16x8*)(Kb + ko0) = pk0; *(bf16x8*)(Kb + ko1) = pk1;
        *(bf16x8*)(Vb + ko0) = pv0; *(bf16x8*)(Vb + ko1) = pv1;
        __syncthreads();

        if (j0 < q0b) {
            pk0 = *(const bf16x8*)(Kg + (size_t)(j0 + 64) * 64);
            pk1 = *(const bf16x8*)(Kg + (size_t)(j0 + 64) * 64 + 8);
            pv0 = *(const bf16x8*)(Vg + j0 + 64);
            pv1 = *(const bf16x8*)(Vg + j0 + 72);
        }

        if (j0 <= q0a)
            attn_step(Kb, Vb, qfA0, qfA1, lpa, oa, qwA, j0, j0 == q0a, col, g, c7);
        attn_step(Kb, Vb, qfB0, qfB1, lpb, ob, qwB, j0, j0 == q0b, col, g, c7);
    }

    // epilogue: l[q=qw+col] lives replicated in the 4 g-lanes of each col group;
    // reduce across g (xor 16/32), then gather l for q=4g+r via lane shuffle.
    float la = lpa; la += __shfl_xor(la, 16); la += __shfl_xor(la, 32);
    float lb = lpb; lb += __shfl_xor(lb, 16); lb += __shfl_xor(lb, 32);
    const int b = bh >> 3, h = bh & 7;
    #pragma unroll
    for (int r = 0; r < 4; ++r) {
        const float inva = 1.f / __shfl(la, 4 * g + r);
        const float invb = 1.f / __shfl(lb, 4 * g + r);
        const size_t rowa = ((size_t)b * 2048 + qwA + 4 * g + r) * 512 + h * 64;
        const size_t rowb = ((size_t)b * 2048 + qwB + 4 * g + r) * 512 + h * 64;
        #pragma unroll
        for (int nt = 0; nt < 4; ++nt) {
            ctxb[rowa + nt * 16 + col] = f2bf(oa[nt][r] * inva);
            ctxb[rowb + nt * 16 + col] = f2bf(ob[nt][r] * invb);
        }
    }
}

// ---------------- LayerNorm(residual): out = LN(A + B1) * g + beta  (2-input)
// One WAVE per row (512 cols / 64 lanes = 8 elems/lane in two coalesced
// float4 passes), pure shfl_xor reduction -- no barriers.
template<int WRITE_BF16>
__global__ __launch_bounds__(256) void ln_residual(const float* __restrict__ A,
                            const float* __restrict__ B1,
                            const float* __restrict__ g, const float* __restrict__ beta,
                            float* __restrict__ out, ushort* __restrict__ outb) {
    const int lane = threadIdx.x & 63;
    const int row  = blockIdx.x * 4 + (threadIdx.x >> 6);
    const size_t base = (size_t)row * D_MODEL;
    const int c0 = lane * 4, c1 = 256 + lane * 4;

    float4 a0 = *(const float4*)&A[base + c0];
    float4 a1 = *(const float4*)&A[base + c1];
    float4 b0 = *(const float4*)&B1[base + c0];
    float4 b1 = *(const float4*)&B1[base + c1];
    float v0 = a0.x + b0.x, v1 = a0.y + b0.y, v2 = a0.z + b0.z, v3 = a0.w + b0.w;
    float v4 = a1.x + b1.x, v5 = a1.y + b1.y, v6 = a1.z + b1.z, v7 = a1.w + b1.w;

    float sum = ((v0 + v1) + (v2 + v3)) + ((v4 + v5) + (v6 + v7));
    #pragma unroll
    for (int off = 32; off; off >>= 1) sum += __shfl_xor(sum, off);
    const float mu = sum * (1.f / 512.f);

    float d0 = v0 - mu, d1 = v1 - mu, d2 = v2 - mu, d3 = v3 - mu;
    float d4 = v4 - mu, d5 = v5 - mu, d6 = v6 - mu, d7 = v7 - mu;
    float sq = ((d0 * d0 + d1 * d1) + (d2 * d2 + d3 * d3))
             + ((d4 * d4 + d5 * d5) + (d6 * d6 + d7 * d7));
    #pragma unroll
    for (int off = 32; off; off >>= 1) sq += __shfl_xor(sq, off);
    const float rs = rsqrtf(sq * (1.f / 512.f) + 1e-5f);

    float4 g0 = *(const float4*)&g[c0],    g1 = *(const float4*)&g[c1];
    float4 e0 = *(const float4*)&beta[c0], e1 = *(const float4*)&beta[c1];
    float4 r0, r1;
    r0.x = d0 * rs * g0.x + e0.x; r0.y = d1 * rs * g0.y + e0.y;
    r0.z = d2 * rs * g0.z + e0.z; r0.w = d3 * rs * g0.w + e0.w;
    r1.x = d4 * rs * g1.x + e1.x; r1.y = d5 * rs * g1.y + e1.y;
    r1.z = d6 * rs * g1.z + e1.z; r1.w = d7 * rs * g1.w + e1.w;
    *(float4*)&out[base + c0] = r0;
    *(float4*)&out[base + c1] = r1;
    if (WRITE_BF16) {
        ushort4 u0, u1;
        u0.x = f2bf(r0.x); u0.y = f2bf(r0.y); u0.z = f2bf(r0.z); u0.w = f2bf(r0.w);
        u1.x = f2bf(r1.x); u1.y = f2bf(r1.y); u1.z = f2bf(r1.z); u1.w = f2bf(r1.w);
        *(ushort4*)&outb[base + c0] = u0;
        *(ushort4*)&outb[base + c1] = u1;
    }
}

extern "C" void kernel_launch(void* const* d_in, const int* in_sizes, int n_in,
                              void* d_out, int out_size, void* d_ws, size_t ws_size,
                              hipStream_t stream) {
    const float* x    = (const float*)d_in[0];
    const float* Wqkv = (const float*)d_in[1];
    const float* bqkv = (const float*)d_in[2];
    const float* Wo   = (const float*)d_in[3];
    const float* bo   = (const float*)d_in[4];
    const float* W1   = (const float*)d_in[5];
    const float* b1   = (const float*)d_in[6];
    const float* W2   = (const float*)d_in[7];
    const float* b2   = (const float*)d_in[8];
    const float* g1   = (const float*)d_in[9];
    const float* bn1  = (const float*)d_in[10];
    const float* g2   = (const float*)d_in[11];
    const float* bn2  = (const float*)d_in[12];

    float* ws = (float*)d_ws;
    // time-multiplexed layout (floats):
    // [0,6291456)    Qcb/Kcb/Vtb (steps 1-2); ff1b [0,8388608) (steps 5-6)
    // [8388608,12582912)  ff2a (steps 6-7)
    // [12582912,16777216) attn_a (steps 3-4)
    // [16777216,20971520) ln1 fp32
    // [20971520,...) ctxb, ln1b, xb, Wqkvb, Wob, W1b, W2b (bf16)
    ushort* Qcb     = (ushort*)ws;
    ushort* Kcb     = (ushort*)(ws + 2097152);
    ushort* Vtb     = (ushort*)(ws + 4194304);
    ushort* ff1b    = (ushort*)ws;
    float*  ff2a    = ws + 8388608;
    float*  attn_a  = ws + 12582912;
    float*  ln1     = ws + 16777216;
    ushort* ctxb  = (ushort*)(ws + 20971520);
    ushort* ln1b  = (ushort*)(ws + 23068672);
    ushort* xb    = (ushort*)(ws + 25165824);
    ushort* Wqkvb = (ushort*)(ws + 27262976);
    float*  out   = (float*)d_out;
    ushort* W1b   = (ushort*)(ws + 27787264);
    ushort* W2b   = (ushort*)(ws + 28311552);
    ushort* Wob   = (ushort*)(ws + 27656192);

    const dim3 blk(256);

    // 0. fused casts (xb..W2b contiguous from xb)
    cast_all_bf16<<<dim3(7168), blk, 0, stream>>>(x, Wqkv, Wo, W1, W2, xb);

    // 1. QKV projection -> split Qc/Kc/Vt bf16 (128x128 depth-3; 768 blk @3/CU)
    gemm_bt_mfma<2,0,128,128><<<dim3(1536/128, 8192/128), blk, 0, stream>>>(
        xb, Wqkvb, bqkv, nullptr, Qcb, Kcb, Vtb, TOKENS, 1536, 512, 512);
    // 2. MFMA flash attention (paired q-tiles, KVBLK=64, reg-prefetch) -> ctxb
    attn_mfma_kernel<<<dim3(512), blk, 0, stream>>>(Qcb, Kcb, Vtb, ctxb);
    // 3. output projection, 64x128 depth-6 group-of-2 -> attn_a fp32 (+bias)
    gemm_bt_mfma<3,0,64,128><<<dim3(512/128, 8192/64), blk, 0, stream>>>(
        ctxb, Wob, bo, attn_a, nullptr, nullptr, nullptr, TOKENS, 512, 512, 512);
    // 4. LN1(x + attn_a) -> ln1 fp32 + ln1b bf16 (1 wave/row, 2048 blocks)
    ln_residual<1><<<dim3(TOKENS/4), blk, 0, stream>>>(x, attn_a, g1, bn1, ln1, ln1b);
    // 5. FF1 + ReLU -> ff1b bf16 [8192,2048]; 128x256 8-wave depth-3:
    //    512 blk @2/CU (72KB LDS, 16 waves/CU) = 1 exact round, 2x B-reuse
    gemm_bt_mfma<1,1,128,256><<<dim3(2048/256, 8192/128), dim3(512), 0, stream>>>(
        ln1b, W1b, b1, ff1b, nullptr, nullptr, nullptr, TOKENS, 2048, 512, 512);
    // 6. FF2, 64x128 depth-6 group-of-2 -> ff2a fp32 (+bias)
    gemm_bt_mfma<3,0,64,128><<<dim3(512/128, 8192/64), blk, 0, stream>>>(
        ff1b, W2b, b2, ff2a, nullptr, nullptr, nullptr, TOKENS, 512, 2048, 2048);
    // 7. LN2(ln1 + ff2a) -> out (1 wave/row, 2048 blocks)
    ln_residual<0><<<dim3(TOKENS/4), blk, 0, stream>>>(ln1, ff2a, g2, bn2, out, nullptr);
}